// Round 3
// baseline (1010.413 us; speedup 1.0000x reference)
//
#include <hip/hip_runtime.h>
#include <hip/hip_bf16.h>

#define N_NODES 50000
#define N_EDGES 800000

// ---------------------------------------------------------------------------
// Static device scratch (module-load allocated; avoids d_ws size uncertainty)
// ---------------------------------------------------------------------------
__device__ int   g_deg[N_NODES];
__device__ int   g_rowstart[N_NODES + 1];
__device__ int   g_cursor[N_NODES];
__device__ int   g_adj[N_EDGES];
__device__ float g_agg[(size_t)N_NODES * 256];
__device__ float g_hA[(size_t)N_NODES * 256];
__device__ float g_hB[(size_t)N_NODES * 256];

__device__ __forceinline__ const float* sel_src(int sel, const float* x) {
    return sel == 0 ? x : (sel == 1 ? (const float*)g_hA : (const float*)g_hB);
}

// ---------------------------------------------------------------------------
// CSR build: zero -> degree count -> exclusive scan -> atomic fill
// edge_index arrives as int32: [src[0..E-1], dst[0..E-1]]
// ---------------------------------------------------------------------------
__global__ void zero_kernel() {
    int i = blockIdx.x * blockDim.x + threadIdx.x;
    if (i < N_NODES) { g_deg[i] = 0; g_cursor[i] = 0; }
}

__global__ void deg_kernel(const int* __restrict__ ei) {
    int e = blockIdx.x * blockDim.x + threadIdx.x;
    if (e >= N_EDGES) return;
    int dst = ei[N_EDGES + e];
    if ((unsigned)dst < N_NODES) atomicAdd(&g_deg[dst], 1);
}

__global__ void scan_kernel() {
    __shared__ int sm[1024];
    __shared__ int running;
    int tid = threadIdx.x;
    if (tid == 0) running = 0;
    __syncthreads();
    for (int base = 0; base < N_NODES; base += 1024) {
        int idx = base + tid;
        int v = (idx < N_NODES) ? g_deg[idx] : 0;
        sm[tid] = v;
        __syncthreads();
        for (int off = 1; off < 1024; off <<= 1) {
            int t = 0;
            if (tid >= off) t = sm[tid - off];
            __syncthreads();
            sm[tid] += t;
            __syncthreads();
        }
        int incl = sm[tid];
        int chunk_total = sm[1023];
        int r = running;
        __syncthreads();
        if (idx < N_NODES) g_rowstart[idx] = r + incl - v;  // exclusive
        if (tid == 0) running += chunk_total;
        __syncthreads();
    }
    if (tid == 0) g_rowstart[N_NODES] = running;
}

__global__ void fill_adj_kernel(const int* __restrict__ ei) {
    int e = blockIdx.x * blockDim.x + threadIdx.x;
    if (e >= N_EDGES) return;
    int src = ei[e];
    int dst = ei[N_EDGES + e];
    if ((unsigned)dst >= N_NODES) return;
    int p = atomicAdd(&g_cursor[dst], 1);
    int idx = g_rowstart[dst] + p;
    if ((unsigned)idx < N_EDGES)
        g_adj[idx] = ((unsigned)src < N_NODES) ? src : 0;
}

// ---------------------------------------------------------------------------
// Mean aggregation: one block per destination node, one thread per feature
// ---------------------------------------------------------------------------
template <int DIN>
__global__ void agg_kernel(const float* __restrict__ xparam, int src_sel) {
    const float* __restrict__ h = sel_src(src_sel, xparam);
    int n = blockIdx.x;
    int t = threadIdx.x;
    int s = g_rowstart[n], e = g_rowstart[n + 1];
    float sum = 0.f;
    int i = s;
    for (; i + 4 <= e; i += 4) {
        int s0 = g_adj[i], s1 = g_adj[i + 1], s2 = g_adj[i + 2], s3 = g_adj[i + 3];
        sum += h[(long)s0 * DIN + t];
        sum += h[(long)s1 * DIN + t];
        sum += h[(long)s2 * DIN + t];
        sum += h[(long)s3 * DIN + t];
    }
    for (; i < e; ++i) sum += h[(long)g_adj[i] * DIN + t];
    float cnt = (float)(e - s);
    g_agg[(long)n * DIN + t] = sum / fmaxf(cnt, 1.0f);
}

// ---------------------------------------------------------------------------
// Fused GEMM: out = g_agg @ W1 + A2 @ W2 + b  (+optional ReLU)
// g_agg/A2: [N_NODES, K] dense, W1/W2: [K, 256], out: [N_NODES, 256]
// Block: 256 threads; tile 64 rows x 256 cols; thread tile 16 rows x 4 cols.
// ---------------------------------------------------------------------------
template <int K, bool RELU>
__global__ __launch_bounds__(256) void gemm2_kernel(
    const float* __restrict__ xparam, int src_sel,
    const float* __restrict__ W1, const float* __restrict__ W2,
    const float* __restrict__ bias, float* __restrict__ outparam, int dst_sel) {
    __shared__ float At[32 * 64];     // At[k][r] transposed A tile
    __shared__ float Wt[32 * 256];    // Wt[k][j]

    const float* A2 = sel_src(src_sel, xparam);
    float* out = dst_sel == 0 ? g_hA : (dst_sel == 1 ? g_hB : outparam);

    int tid = threadIdx.x;
    int cg = tid & 63;    // column group: cols cg*4 .. cg*4+3
    int rg = tid >> 6;    // row group: rows rg*16 .. rg*16+15
    long row0 = (long)blockIdx.x * 64;

    float acc[16][4];
#pragma unroll
    for (int i = 0; i < 16; ++i)
#pragma unroll
        for (int j = 0; j < 4; ++j) acc[i][j] = 0.f;

#pragma unroll
    for (int p = 0; p < 2; ++p) {
        const float* A = p ? A2 : (const float*)g_agg;
        const float* W = p ? W2 : W1;
        for (int kc = 0; kc < K; kc += 32) {
            __syncthreads();
            {   // load A tile (64 rows x 32 k), store transposed
                int r = tid >> 2;           // 0..63
                int kq = (tid & 3) * 8;     // 0,8,16,24
                long gr = row0 + r;
                if (gr >= N_NODES) gr = N_NODES - 1;
                const float* srcp = &A[gr * K + kc + kq];
                float4 v0 = *(const float4*)(srcp);
                float4 v1 = *(const float4*)(srcp + 4);
                At[(kq + 0) * 64 + r] = v0.x;
                At[(kq + 1) * 64 + r] = v0.y;
                At[(kq + 2) * 64 + r] = v0.z;
                At[(kq + 3) * 64 + r] = v0.w;
                At[(kq + 4) * 64 + r] = v1.x;
                At[(kq + 5) * 64 + r] = v1.y;
                At[(kq + 6) * 64 + r] = v1.z;
                At[(kq + 7) * 64 + r] = v1.w;
            }
            {   // load W tile (32 k x 256 cols), linear
                int k = tid >> 3;           // 0..31
                int jq = (tid & 7) * 32;
                const float* srcp = &W[(long)(kc + k) * 256 + jq];
#pragma unroll
                for (int q = 0; q < 8; ++q) {
                    float4 v = *(const float4*)(srcp + q * 4);
                    *(float4*)&Wt[k * 256 + jq + q * 4] = v;
                }
            }
            __syncthreads();
#pragma unroll
            for (int k = 0; k < 32; ++k) {
                float4 wv = *(const float4*)&Wt[k * 256 + cg * 4];
#pragma unroll
                for (int rq = 0; rq < 4; ++rq) {
                    float4 av = *(const float4*)&At[k * 64 + rg * 16 + rq * 4];
                    acc[rq * 4 + 0][0] += av.x * wv.x;
                    acc[rq * 4 + 0][1] += av.x * wv.y;
                    acc[rq * 4 + 0][2] += av.x * wv.z;
                    acc[rq * 4 + 0][3] += av.x * wv.w;
                    acc[rq * 4 + 1][0] += av.y * wv.x;
                    acc[rq * 4 + 1][1] += av.y * wv.y;
                    acc[rq * 4 + 1][2] += av.y * wv.z;
                    acc[rq * 4 + 1][3] += av.y * wv.w;
                    acc[rq * 4 + 2][0] += av.z * wv.x;
                    acc[rq * 4 + 2][1] += av.z * wv.y;
                    acc[rq * 4 + 2][2] += av.z * wv.z;
                    acc[rq * 4 + 2][3] += av.z * wv.w;
                    acc[rq * 4 + 3][0] += av.w * wv.x;
                    acc[rq * 4 + 3][1] += av.w * wv.y;
                    acc[rq * 4 + 3][2] += av.w * wv.z;
                    acc[rq * 4 + 3][3] += av.w * wv.w;
                }
            }
        }
    }

    float4 bv = *(const float4*)&bias[cg * 4];
#pragma unroll
    for (int i = 0; i < 16; ++i) {
        long gr = row0 + rg * 16 + i;
        if (gr < N_NODES) {
            float4 o;
            o.x = acc[i][0] + bv.x;
            o.y = acc[i][1] + bv.y;
            o.z = acc[i][2] + bv.z;
            o.w = acc[i][3] + bv.w;
            if (RELU) {
                o.x = fmaxf(o.x, 0.f);
                o.y = fmaxf(o.y, 0.f);
                o.z = fmaxf(o.z, 0.f);
                o.w = fmaxf(o.w, 0.f);
            }
            *(float4*)&out[gr * 256 + cg * 4] = o;
        }
    }
}

// ---------------------------------------------------------------------------
extern "C" void kernel_launch(void* const* d_in, const int* in_sizes, int n_in,
                              void* d_out, int out_size, void* d_ws, size_t ws_size,
                              hipStream_t stream) {
    const float* x = (const float*)d_in[0];
    const int* ei = (const int*)d_in[1];        // int32! [2, E] row-major
    const float* Wl0 = (const float*)d_in[2];
    const float* b0  = (const float*)d_in[3];
    const float* Wr0 = (const float*)d_in[4];
    const float* Wl1 = (const float*)d_in[5];
    const float* b1  = (const float*)d_in[6];
    const float* Wr1 = (const float*)d_in[7];
    const float* Wl2 = (const float*)d_in[8];
    const float* b2  = (const float*)d_in[9];
    const float* Wr2 = (const float*)d_in[10];
    float* out = (float*)d_out;

    int eblocks = (N_EDGES + 255) / 256;
    int nblocks = (N_NODES + 255) / 256;

    zero_kernel<<<nblocks, 256, 0, stream>>>();
    deg_kernel<<<eblocks, 256, 0, stream>>>(ei);
    scan_kernel<<<1, 1024, 0, stream>>>();
    fill_adj_kernel<<<eblocks, 256, 0, stream>>>(ei);

    int gblocks = (N_NODES + 63) / 64;   // 782

    // Layer 0: din=128   (agg <- x, root <- x, out -> g_hA)
    agg_kernel<128><<<N_NODES, 128, 0, stream>>>(x, 0);
    gemm2_kernel<128, true><<<gblocks, 256, 0, stream>>>(x, 0, Wl0, Wr0, b0, nullptr, 0);

    // Layer 1: din=256   (agg <- g_hA, out -> g_hB)
    agg_kernel<256><<<N_NODES, 256, 0, stream>>>(nullptr, 1);
    gemm2_kernel<256, true><<<gblocks, 256, 0, stream>>>(nullptr, 1, Wl1, Wr1, b1, nullptr, 1);

    // Layer 2: din=256, no ReLU  (agg <- g_hB, out -> d_out)
    agg_kernel<256><<<N_NODES, 256, 0, stream>>>(nullptr, 2);
    gemm2_kernel<256, false><<<gblocks, 256, 0, stream>>>(nullptr, 2, Wl2, Wr2, b2, out, 2);
}

// Round 4
// 741.234 us; speedup vs baseline: 1.3631x; 1.3631x over previous
//
#include <hip/hip_runtime.h>
#include <hip/hip_bf16.h>

#define N_NODES 50000
#define N_EDGES 800000

typedef __attribute__((ext_vector_type(4))) float f32x4;
typedef __attribute__((ext_vector_type(8))) short s16x8;

// ---------------------------------------------------------------------------
// Static device scratch
// ---------------------------------------------------------------------------
__device__ int   g_deg[N_NODES];
__device__ int   g_rowstart[N_NODES + 1];
__device__ int   g_cursor[N_NODES];
__device__ int   g_adj[N_EDGES];
__device__ __attribute__((aligned(256))) float g_agg[(size_t)N_NODES * 256];
__device__ __attribute__((aligned(256))) float g_hA[(size_t)N_NODES * 256];
__device__ __attribute__((aligned(256))) float g_hB[(size_t)N_NODES * 256];
// split-bf16 transposed weights: [matrix][n*K + k]
__device__ __attribute__((aligned(256))) unsigned short g_Whi[6][256 * 256];
__device__ __attribute__((aligned(256))) unsigned short g_Wlo[6][256 * 256];

__device__ __forceinline__ const float* sel_src(int sel, const float* x) {
    return sel == 0 ? x : (sel == 1 ? (const float*)g_hA : (const float*)g_hB);
}

__device__ __forceinline__ unsigned short f2bf(float f) {
    unsigned int u = __float_as_uint(f);
    unsigned int r = (u + 0x7fffu + ((u >> 16) & 1u)) >> 16;   // RNE
    return (unsigned short)r;
}
__device__ __forceinline__ float bf2f(unsigned short h) {
    return __uint_as_float(((unsigned int)h) << 16);
}

// ---------------------------------------------------------------------------
// CSR build: zero -> degree count -> exclusive scan -> atomic fill
// edge_index arrives as int32: [src[0..E-1], dst[0..E-1]]
// ---------------------------------------------------------------------------
__global__ void zero_kernel() {
    int i = blockIdx.x * blockDim.x + threadIdx.x;
    if (i < N_NODES) { g_deg[i] = 0; g_cursor[i] = 0; }
}

__global__ void deg_kernel(const int* __restrict__ ei) {
    int e = blockIdx.x * blockDim.x + threadIdx.x;
    if (e >= N_EDGES) return;
    int dst = ei[N_EDGES + e];
    if ((unsigned)dst < N_NODES) atomicAdd(&g_deg[dst], 1);
}

__global__ void scan_kernel() {
    __shared__ int sm[1024];
    __shared__ int running;
    int tid = threadIdx.x;
    if (tid == 0) running = 0;
    __syncthreads();
    for (int base = 0; base < N_NODES; base += 1024) {
        int idx = base + tid;
        int v = (idx < N_NODES) ? g_deg[idx] : 0;
        sm[tid] = v;
        __syncthreads();
        for (int off = 1; off < 1024; off <<= 1) {
            int t = 0;
            if (tid >= off) t = sm[tid - off];
            __syncthreads();
            sm[tid] += t;
            __syncthreads();
        }
        int incl = sm[tid];
        int chunk_total = sm[1023];
        int r = running;
        __syncthreads();
        if (idx < N_NODES) g_rowstart[idx] = r + incl - v;  // exclusive
        if (tid == 0) running += chunk_total;
        __syncthreads();
    }
    if (tid == 0) g_rowstart[N_NODES] = running;
}

__global__ void fill_adj_kernel(const int* __restrict__ ei) {
    int e = blockIdx.x * blockDim.x + threadIdx.x;
    if (e >= N_EDGES) return;
    int src = ei[e];
    int dst = ei[N_EDGES + e];
    if ((unsigned)dst >= N_NODES) return;
    int p = atomicAdd(&g_cursor[dst], 1);
    int idx = g_rowstart[dst] + p;
    if ((unsigned)idx < N_EDGES)
        g_adj[idx] = ((unsigned)src < N_NODES) ? src : 0;
}

// ---------------------------------------------------------------------------
// Weight prep: W [K][256] fp32 -> transposed split bf16 Wt[n][k] (hi, lo)
// ---------------------------------------------------------------------------
__global__ void prep_w_kernel(const float* __restrict__ W, int K, int idx) {
    int e = blockIdx.x * 256 + threadIdx.x;
    if (e >= K * 256) return;
    int k = e >> 8, n = e & 255;
    float w = W[e];
    unsigned short hi = f2bf(w);
    unsigned short lo = f2bf(w - bf2f(hi));
    g_Whi[idx][n * K + k] = hi;
    g_Wlo[idx][n * K + k] = lo;
}

// ---------------------------------------------------------------------------
// Mean aggregation: one block per destination node, one thread per feature
// ---------------------------------------------------------------------------
template <int DIN>
__global__ void agg_kernel(const float* __restrict__ xparam, int src_sel) {
    const float* __restrict__ h = sel_src(src_sel, xparam);
    int n = blockIdx.x;
    int t = threadIdx.x;
    int s = g_rowstart[n], e = g_rowstart[n + 1];
    float sum = 0.f;
    int i = s;
    for (; i + 4 <= e; i += 4) {
        int s0 = g_adj[i], s1 = g_adj[i + 1], s2 = g_adj[i + 2], s3 = g_adj[i + 3];
        sum += h[(long)s0 * DIN + t];
        sum += h[(long)s1 * DIN + t];
        sum += h[(long)s2 * DIN + t];
        sum += h[(long)s3 * DIN + t];
    }
    for (; i < e; ++i) sum += h[(long)g_adj[i] * DIN + t];
    float cnt = (float)(e - s);
    g_agg[(long)n * DIN + t] = sum / fmaxf(cnt, 1.0f);
}

// ---------------------------------------------------------------------------
// MFMA split-bf16 dual GEMM: out = g_agg @ W[widx] + A2 @ W[widx+1] + b (+ReLU)
// Block: 256 thr (4 waves). BM=64, BN=256, BK=64. Wave w: rows 0..63 x cols
// w*64..w*64+63 as 4x4 frags of 16x16x32_bf16. 3 MFMAs per frag (hi*hi,
// hi*lo, lo*hi). LDS rows 128B, XOR-swizzle byte ^= (row&7)<<4.
// ---------------------------------------------------------------------------
template <int K, bool RELU>
__global__ __launch_bounds__(256) void gemm2_mfma(
    const float* __restrict__ xparam, int src_sel, int widx,
    const float* __restrict__ bias, float* __restrict__ outparam, int dst_sel) {
    __shared__ __attribute__((aligned(16))) char lds[81920];
    char* const As_hi = lds;             // 64 rows * 128B = 8192
    char* const As_lo = lds + 8192;      // 8192
    char* const Ws_hi = lds + 16384;     // 256 rows * 128B = 32768
    char* const Ws_lo = lds + 49152;     // 32768

    const float* A2 = sel_src(src_sel, xparam);
    float* out = dst_sel == 0 ? g_hA : (dst_sel == 1 ? g_hB : outparam);

    const int tid = threadIdx.x;
    const int wv = tid >> 6;
    const int l = tid & 63;
    const int l16 = l & 15;
    const int lk = l >> 4;              // k-group 0..3
    const int n0 = wv * 64;
    const long row0 = (long)blockIdx.x * 64;

    f32x4 acc[4][4];
#pragma unroll
    for (int i = 0; i < 4; ++i)
#pragma unroll
        for (int j = 0; j < 4; ++j) acc[i][j] = (f32x4)0.f;

    // A staging geometry: thread -> (row, 16-float chunk)
    const int ar = tid >> 2;              // 0..63
    const int ae0 = (tid & 3) * 16;       // element offset in row: 0,16,32,48
    const int ab0 = ae0 * 2;              // byte offset in 128B LDS row
    const int asw = (ar & 7) << 4;
    long agr = row0 + ar; if (agr > N_NODES - 1) agr = N_NODES - 1;
    // W staging geometry: thread -> one n-row of 64 bf16 (128B)
    const int wn = tid;                   // 0..255
    const int wsw = (wn & 7) << 4;

#pragma unroll
    for (int pass = 0; pass < 2; ++pass) {
        const float* A = pass ? A2 : (const float*)g_agg;
        const unsigned short* WH = g_Whi[widx + pass];
        const unsigned short* WL = g_Wlo[widx + pass];
        for (int kc = 0; kc < K; kc += 64) {
            __syncthreads();
            {   // stage A chunk: 64 rows x 64 k fp32 -> split bf16
                const float* ap = &A[agr * K + kc + ae0];
                f32x4 f0 = *(const f32x4*)(ap + 0);
                f32x4 f1 = *(const f32x4*)(ap + 4);
                f32x4 f2 = *(const f32x4*)(ap + 8);
                f32x4 f3 = *(const f32x4*)(ap + 12);
                float fa[16];
                *(f32x4*)(fa + 0) = f0;
                *(f32x4*)(fa + 4) = f1;
                *(f32x4*)(fa + 8) = f2;
                *(f32x4*)(fa + 12) = f3;
                s16x8 vh0, vh1, vl0, vl1;
#pragma unroll
                for (int i = 0; i < 8; ++i) {
                    unsigned short h = f2bf(fa[i]);
                    vh0[i] = (short)h;
                    vl0[i] = (short)f2bf(fa[i] - bf2f(h));
                }
#pragma unroll
                for (int i = 0; i < 8; ++i) {
                    unsigned short h = f2bf(fa[8 + i]);
                    vh1[i] = (short)h;
                    vl1[i] = (short)f2bf(fa[8 + i] - bf2f(h));
                }
                *(s16x8*)(As_hi + ar * 128 + ((ab0 + 0) ^ asw)) = vh0;
                *(s16x8*)(As_hi + ar * 128 + ((ab0 + 16) ^ asw)) = vh1;
                *(s16x8*)(As_lo + ar * 128 + ((ab0 + 0) ^ asw)) = vl0;
                *(s16x8*)(As_lo + ar * 128 + ((ab0 + 16) ^ asw)) = vl1;
            }
            {   // stage W chunk: 256 n-rows x 64 k bf16 (hi+lo)
                const unsigned short* wh = WH + (long)wn * K + kc;
                const unsigned short* wl = WL + (long)wn * K + kc;
#pragma unroll
                for (int j = 0; j < 8; ++j) {
                    *(s16x8*)(Ws_hi + wn * 128 + ((j * 16) ^ wsw)) = *(const s16x8*)(wh + j * 8);
                    *(s16x8*)(Ws_lo + wn * 128 + ((j * 16) ^ wsw)) = *(const s16x8*)(wl + j * 8);
                }
            }
            __syncthreads();
#pragma unroll
            for (int ks = 0; ks < 2; ++ks) {
                const int kb = ks * 64 + lk * 16;   // byte-in-row for this lane's k-slice
                s16x8 ah[4], al[4], bh[4], bl[4];
#pragma unroll
                for (int mi = 0; mi < 4; ++mi) {
                    int row = mi * 16 + l16;
                    int off = row * 128 + (kb ^ ((row & 7) << 4));
                    ah[mi] = *(const s16x8*)(As_hi + off);
                    al[mi] = *(const s16x8*)(As_lo + off);
                }
#pragma unroll
                for (int ni = 0; ni < 4; ++ni) {
                    int n = n0 + ni * 16 + l16;
                    int off = n * 128 + (kb ^ ((n & 7) << 4));
                    bh[ni] = *(const s16x8*)(Ws_hi + off);
                    bl[ni] = *(const s16x8*)(Ws_lo + off);
                }
#pragma unroll
                for (int mi = 0; mi < 4; ++mi)
#pragma unroll
                    for (int ni = 0; ni < 4; ++ni) {
                        acc[mi][ni] = __builtin_amdgcn_mfma_f32_16x16x32_bf16(ah[mi], bh[ni], acc[mi][ni], 0, 0, 0);
                        acc[mi][ni] = __builtin_amdgcn_mfma_f32_16x16x32_bf16(ah[mi], bl[ni], acc[mi][ni], 0, 0, 0);
                        acc[mi][ni] = __builtin_amdgcn_mfma_f32_16x16x32_bf16(al[mi], bh[ni], acc[mi][ni], 0, 0, 0);
                    }
            }
        }
    }

    // epilogue: D col = lane&15, row = (lane>>4)*4 + r   [m89-verified layout]
#pragma unroll
    for (int ni = 0; ni < 4; ++ni) {
        int col = n0 + ni * 16 + l16;
        float bv = bias[col];
#pragma unroll
        for (int mi = 0; mi < 4; ++mi) {
#pragma unroll
            for (int r = 0; r < 4; ++r) {
                long grow = row0 + mi * 16 + lk * 4 + r;
                if (grow < N_NODES) {
                    float v = acc[mi][ni][r] + bv;
                    if (RELU) v = fmaxf(v, 0.f);
                    out[grow * 256 + col] = v;
                }
            }
        }
    }
}

// ---------------------------------------------------------------------------
extern "C" void kernel_launch(void* const* d_in, const int* in_sizes, int n_in,
                              void* d_out, int out_size, void* d_ws, size_t ws_size,
                              hipStream_t stream) {
    const float* x = (const float*)d_in[0];
    const int* ei = (const int*)d_in[1];        // int32 [2, E]
    const float* Wl0 = (const float*)d_in[2];
    const float* b0  = (const float*)d_in[3];
    const float* Wr0 = (const float*)d_in[4];
    const float* Wl1 = (const float*)d_in[5];
    const float* b1  = (const float*)d_in[6];
    const float* Wr1 = (const float*)d_in[7];
    const float* Wl2 = (const float*)d_in[8];
    const float* b2  = (const float*)d_in[9];
    const float* Wr2 = (const float*)d_in[10];
    float* out = (float*)d_out;

    int eblocks = (N_EDGES + 255) / 256;
    int nblocks = (N_NODES + 255) / 256;

    zero_kernel<<<nblocks, 256, 0, stream>>>();
    deg_kernel<<<eblocks, 256, 0, stream>>>(ei);
    scan_kernel<<<1, 1024, 0, stream>>>();
    fill_adj_kernel<<<eblocks, 256, 0, stream>>>(ei);

    // weight prep (split + transpose), tiny
    prep_w_kernel<<<128, 256, 0, stream>>>(Wl0, 128, 0);
    prep_w_kernel<<<128, 256, 0, stream>>>(Wr0, 128, 1);
    prep_w_kernel<<<256, 256, 0, stream>>>(Wl1, 256, 2);
    prep_w_kernel<<<256, 256, 0, stream>>>(Wr1, 256, 3);
    prep_w_kernel<<<256, 256, 0, stream>>>(Wl2, 256, 4);
    prep_w_kernel<<<256, 256, 0, stream>>>(Wr2, 256, 5);

    int gblocks = (N_NODES + 63) / 64;   // 782

    // Layer 0: din=128   (agg <- x, root <- x, out -> g_hA)
    agg_kernel<128><<<N_NODES, 128, 0, stream>>>(x, 0);
    gemm2_mfma<128, true><<<gblocks, 256, 0, stream>>>(x, 0, 0, b0, nullptr, 0);

    // Layer 1: din=256   (agg <- g_hA, out -> g_hB)
    agg_kernel<256><<<N_NODES, 256, 0, stream>>>(nullptr, 1);
    gemm2_mfma<256, true><<<gblocks, 256, 0, stream>>>(nullptr, 1, 2, b1, nullptr, 1);

    // Layer 2: din=256, no ReLU  (agg <- g_hB, out -> d_out)
    agg_kernel<256><<<N_NODES, 256, 0, stream>>>(nullptr, 2);
    gemm2_mfma<256, false><<<gblocks, 256, 0, stream>>>(nullptr, 2, 4, b2, out, 2);
}

// Round 5
// 597.693 us; speedup vs baseline: 1.6905x; 1.2402x over previous
//
#include <hip/hip_runtime.h>
#include <hip/hip_bf16.h>

#define N_NODES 50000
#define N_EDGES 800000

typedef __attribute__((ext_vector_type(4))) float f32x4;
typedef __attribute__((ext_vector_type(8))) short s16x8;

// ---------------------------------------------------------------------------
// Static device scratch
// ---------------------------------------------------------------------------
__device__ int   g_deg[N_NODES];
__device__ int   g_rowstart[N_NODES + 1];
__device__ int   g_cursor[N_NODES];
__device__ int   g_adj[N_EDGES];
__device__ int   g_bsum[256];
__device__ int   g_boff[256];
__device__ __attribute__((aligned(256))) float g_agg[(size_t)N_NODES * 256];
__device__ __attribute__((aligned(256))) float g_hA[(size_t)N_NODES * 256];
__device__ __attribute__((aligned(256))) float g_hB[(size_t)N_NODES * 256];
// bf16 copy of the CURRENT layer's input features (for the gather)
__device__ __attribute__((aligned(256))) unsigned short g_hbf[(size_t)N_NODES * 256];
// split-bf16 transposed weights: [matrix][n*K + k]
__device__ __attribute__((aligned(256))) unsigned short g_Whi[6][256 * 256];
__device__ __attribute__((aligned(256))) unsigned short g_Wlo[6][256 * 256];

__device__ __forceinline__ const float* sel_src(int sel, const float* x) {
    return sel == 0 ? x : (sel == 1 ? (const float*)g_hA : (const float*)g_hB);
}

__device__ __forceinline__ unsigned short f2bf(float f) {
    unsigned int u = __float_as_uint(f);
    unsigned int r = (u + 0x7fffu + ((u >> 16) & 1u)) >> 16;   // RNE
    return (unsigned short)r;
}
__device__ __forceinline__ float bf2f(unsigned short h) {
    return __uint_as_float(((unsigned int)h) << 16);
}

// ---------------------------------------------------------------------------
// CSR build: zero -> degree count -> 3-kernel scan -> atomic fill
// edge_index arrives as int32: [src[0..E-1], dst[0..E-1]]
// ---------------------------------------------------------------------------
__global__ void zero_kernel() {
    int i = blockIdx.x * blockDim.x + threadIdx.x;
    if (i < N_NODES) { g_deg[i] = 0; g_cursor[i] = 0; }
}

__global__ void deg_kernel(const int* __restrict__ ei) {
    int e = blockIdx.x * blockDim.x + threadIdx.x;
    if (e >= N_EDGES) return;
    int dst = ei[N_EDGES + e];
    if ((unsigned)dst < N_NODES) atomicAdd(&g_deg[dst], 1);
}

__global__ void scan1_kernel() {
    __shared__ int sm[256];
    int t = threadIdx.x;
    int idx = blockIdx.x * 256 + t;
    sm[t] = (idx < N_NODES) ? g_deg[idx] : 0;
    __syncthreads();
    for (int off = 128; off > 0; off >>= 1) {
        if (t < off) sm[t] += sm[t + off];
        __syncthreads();
    }
    if (t == 0) g_bsum[blockIdx.x] = sm[0];
}

__global__ void scan2_kernel(int nb) {
    __shared__ int sm[256];
    int t = threadIdx.x;
    int v = (t < nb) ? g_bsum[t] : 0;
    sm[t] = v;
    __syncthreads();
    for (int off = 1; off < 256; off <<= 1) {
        int tv = (t >= off) ? sm[t - off] : 0;
        __syncthreads();
        sm[t] += tv;
        __syncthreads();
    }
    g_boff[t] = sm[t] - v;                 // exclusive block offset
    if (t == nb - 1) g_rowstart[N_NODES] = sm[t];
}

__global__ void scan3_kernel() {
    __shared__ int sm[256];
    int t = threadIdx.x;
    int idx = blockIdx.x * 256 + t;
    int v = (idx < N_NODES) ? g_deg[idx] : 0;
    sm[t] = v;
    __syncthreads();
    for (int off = 1; off < 256; off <<= 1) {
        int tv = (t >= off) ? sm[t - off] : 0;
        __syncthreads();
        sm[t] += tv;
        __syncthreads();
    }
    if (idx < N_NODES) g_rowstart[idx] = g_boff[blockIdx.x] + sm[t] - v;
}

__global__ void fill_adj_kernel(const int* __restrict__ ei) {
    int e = blockIdx.x * blockDim.x + threadIdx.x;
    if (e >= N_EDGES) return;
    int src = ei[e];
    int dst = ei[N_EDGES + e];
    if ((unsigned)dst >= N_NODES) return;
    int p = atomicAdd(&g_cursor[dst], 1);
    int idx = g_rowstart[dst] + p;
    if ((unsigned)idx < N_EDGES)
        g_adj[idx] = ((unsigned)src < N_NODES) ? src : 0;
}

// ---------------------------------------------------------------------------
// Weight prep: W [K][256] fp32 -> transposed split bf16 Wt[n][k] (hi, lo)
// ---------------------------------------------------------------------------
__global__ void prep_w_kernel(const float* __restrict__ W, int K, int idx) {
    int e = blockIdx.x * 256 + threadIdx.x;
    if (e >= K * 256) return;
    int k = e >> 8, n = e & 255;
    float w = W[e];
    unsigned short hi = f2bf(w);
    unsigned short lo = f2bf(w - bf2f(hi));
    g_Whi[idx][n * K + k] = hi;
    g_Wlo[idx][n * K + k] = lo;
}

// x (N x 128 fp32) -> g_hbf bf16
__global__ void conv_x_kernel(const float* __restrict__ x) {
    int i = blockIdx.x * 256 + threadIdx.x;   // quad index
    if (i >= N_NODES * 128 / 4) return;
    f32x4 v = *(const f32x4*)(x + (size_t)i * 4);
    unsigned long long p = (unsigned long long)f2bf(v.x)
                         | ((unsigned long long)f2bf(v.y) << 16)
                         | ((unsigned long long)f2bf(v.z) << 32)
                         | ((unsigned long long)f2bf(v.w) << 48);
    *(unsigned long long*)(g_hbf + (size_t)i * 4) = p;
}

// ---------------------------------------------------------------------------
// Mean aggregation (bf16 gather): one block per dst node, one thread/feature
// ---------------------------------------------------------------------------
template <int DIN>
__global__ __launch_bounds__(DIN) void agg_bf_kernel() {
    const unsigned short* __restrict__ hb = g_hbf;
    int n = blockIdx.x;
    int t = threadIdx.x;
    int s = g_rowstart[n], e = g_rowstart[n + 1];
    float sum = 0.f;
    int i = s;
    for (; i + 8 <= e; i += 8) {
        int a0 = g_adj[i + 0], a1 = g_adj[i + 1], a2 = g_adj[i + 2], a3 = g_adj[i + 3];
        int a4 = g_adj[i + 4], a5 = g_adj[i + 5], a6 = g_adj[i + 6], a7 = g_adj[i + 7];
        unsigned short u0 = hb[(long)a0 * DIN + t];
        unsigned short u1 = hb[(long)a1 * DIN + t];
        unsigned short u2 = hb[(long)a2 * DIN + t];
        unsigned short u3 = hb[(long)a3 * DIN + t];
        unsigned short u4 = hb[(long)a4 * DIN + t];
        unsigned short u5 = hb[(long)a5 * DIN + t];
        unsigned short u6 = hb[(long)a6 * DIN + t];
        unsigned short u7 = hb[(long)a7 * DIN + t];
        sum += bf2f(u0) + bf2f(u1) + bf2f(u2) + bf2f(u3)
             + bf2f(u4) + bf2f(u5) + bf2f(u6) + bf2f(u7);
    }
    for (; i < e; ++i) sum += bf2f(hb[(long)g_adj[i] * DIN + t]);
    float cnt = (float)(e - s);
    g_agg[(long)n * DIN + t] = sum / fmaxf(cnt, 1.0f);
}

// ---------------------------------------------------------------------------
// MFMA split-bf16 dual GEMM: out = g_agg @ W[widx] + A2 @ W[widx+1] + b (+ReLU)
// Block: 256 thr (4 waves). BM=64, BN=256, BK=64. 3 MFMAs per frag pair
// (hi*hi, hi*lo, lo*hi). LDS rows 128B, XOR-swizzle byte ^= (row&7)<<4.
// BFOUT: also write bf16 copy of the output into g_hbf (next layer's gather).
// ---------------------------------------------------------------------------
template <int K, bool RELU, bool BFOUT>
__global__ __launch_bounds__(256) void gemm2_mfma(
    const float* __restrict__ xparam, int src_sel, int widx,
    const float* __restrict__ bias, float* __restrict__ outparam, int dst_sel) {
    __shared__ __attribute__((aligned(16))) char lds[81920];
    char* const As_hi = lds;             // 64 rows * 128B = 8192
    char* const As_lo = lds + 8192;      // 8192
    char* const Ws_hi = lds + 16384;     // 256 rows * 128B = 32768
    char* const Ws_lo = lds + 49152;     // 32768

    const float* A2 = sel_src(src_sel, xparam);
    float* out = dst_sel == 0 ? g_hA : (dst_sel == 1 ? g_hB : outparam);

    const int tid = threadIdx.x;
    const int wv = tid >> 6;
    const int l = tid & 63;
    const int l16 = l & 15;
    const int lk = l >> 4;              // k-group 0..3
    const int n0 = wv * 64;
    const long row0 = (long)blockIdx.x * 64;

    f32x4 acc[4][4];
#pragma unroll
    for (int i = 0; i < 4; ++i)
#pragma unroll
        for (int j = 0; j < 4; ++j) acc[i][j] = (f32x4)0.f;

    // A staging geometry: thread -> (row, 16-float chunk)
    const int ar = tid >> 2;              // 0..63
    const int ae0 = (tid & 3) * 16;       // element offset in row: 0,16,32,48
    const int ab0 = ae0 * 2;              // byte offset in 128B LDS row
    const int asw = (ar & 7) << 4;
    long agr = row0 + ar; if (agr > N_NODES - 1) agr = N_NODES - 1;
    // W staging geometry: thread -> one n-row of 64 bf16 (128B)
    const int wn = tid;                   // 0..255
    const int wsw = (wn & 7) << 4;

#pragma unroll
    for (int pass = 0; pass < 2; ++pass) {
        const float* A = pass ? A2 : (const float*)g_agg;
        const unsigned short* WH = g_Whi[widx + pass];
        const unsigned short* WL = g_Wlo[widx + pass];
        for (int kc = 0; kc < K; kc += 64) {
            __syncthreads();
            {   // stage A chunk: 64 rows x 64 k fp32 -> split bf16
                const float* ap = &A[agr * K + kc + ae0];
                f32x4 f0 = *(const f32x4*)(ap + 0);
                f32x4 f1 = *(const f32x4*)(ap + 4);
                f32x4 f2 = *(const f32x4*)(ap + 8);
                f32x4 f3 = *(const f32x4*)(ap + 12);
                float fa[16];
                *(f32x4*)(fa + 0) = f0;
                *(f32x4*)(fa + 4) = f1;
                *(f32x4*)(fa + 8) = f2;
                *(f32x4*)(fa + 12) = f3;
                s16x8 vh0, vh1, vl0, vl1;
#pragma unroll
                for (int i = 0; i < 8; ++i) {
                    unsigned short h = f2bf(fa[i]);
                    vh0[i] = (short)h;
                    vl0[i] = (short)f2bf(fa[i] - bf2f(h));
                }
#pragma unroll
                for (int i = 0; i < 8; ++i) {
                    unsigned short h = f2bf(fa[8 + i]);
                    vh1[i] = (short)h;
                    vl1[i] = (short)f2bf(fa[8 + i] - bf2f(h));
                }
                *(s16x8*)(As_hi + ar * 128 + ((ab0 + 0) ^ asw)) = vh0;
                *(s16x8*)(As_hi + ar * 128 + ((ab0 + 16) ^ asw)) = vh1;
                *(s16x8*)(As_lo + ar * 128 + ((ab0 + 0) ^ asw)) = vl0;
                *(s16x8*)(As_lo + ar * 128 + ((ab0 + 16) ^ asw)) = vl1;
            }
            {   // stage W chunk: 256 n-rows x 64 k bf16 (hi+lo)
                const unsigned short* wh = WH + (long)wn * K + kc;
                const unsigned short* wl = WL + (long)wn * K + kc;
#pragma unroll
                for (int j = 0; j < 8; ++j) {
                    *(s16x8*)(Ws_hi + wn * 128 + ((j * 16) ^ wsw)) = *(const s16x8*)(wh + j * 8);
                    *(s16x8*)(Ws_lo + wn * 128 + ((j * 16) ^ wsw)) = *(const s16x8*)(wl + j * 8);
                }
            }
            __syncthreads();
#pragma unroll
            for (int ks = 0; ks < 2; ++ks) {
                const int kb = ks * 64 + lk * 16;   // byte-in-row for this lane's k-slice
                s16x8 ah[4], al[4], bh[4], bl[4];
#pragma unroll
                for (int mi = 0; mi < 4; ++mi) {
                    int row = mi * 16 + l16;
                    int off = row * 128 + (kb ^ ((row & 7) << 4));
                    ah[mi] = *(const s16x8*)(As_hi + off);
                    al[mi] = *(const s16x8*)(As_lo + off);
                }
#pragma unroll
                for (int ni = 0; ni < 4; ++ni) {
                    int n = n0 + ni * 16 + l16;
                    int off = n * 128 + (kb ^ ((n & 7) << 4));
                    bh[ni] = *(const s16x8*)(Ws_hi + off);
                    bl[ni] = *(const s16x8*)(Ws_lo + off);
                }
#pragma unroll
                for (int mi = 0; mi < 4; ++mi)
#pragma unroll
                    for (int ni = 0; ni < 4; ++ni) {
                        acc[mi][ni] = __builtin_amdgcn_mfma_f32_16x16x32_bf16(ah[mi], bh[ni], acc[mi][ni], 0, 0, 0);
                        acc[mi][ni] = __builtin_amdgcn_mfma_f32_16x16x32_bf16(ah[mi], bl[ni], acc[mi][ni], 0, 0, 0);
                        acc[mi][ni] = __builtin_amdgcn_mfma_f32_16x16x32_bf16(al[mi], bh[ni], acc[mi][ni], 0, 0, 0);
                    }
            }
        }
    }

    // epilogue: D col = lane&15, row = (lane>>4)*4 + r   [m89-verified layout]
#pragma unroll
    for (int ni = 0; ni < 4; ++ni) {
        int col = n0 + ni * 16 + l16;
        float bv = bias[col];
#pragma unroll
        for (int mi = 0; mi < 4; ++mi) {
#pragma unroll
            for (int r = 0; r < 4; ++r) {
                long grow = row0 + mi * 16 + lk * 4 + r;
                if (grow < N_NODES) {
                    float v = acc[mi][ni][r] + bv;
                    if (RELU) v = fmaxf(v, 0.f);
                    out[grow * 256 + col] = v;
                    if (BFOUT) g_hbf[grow * 256 + col] = f2bf(v);
                }
            }
        }
    }
}

// ---------------------------------------------------------------------------
extern "C" void kernel_launch(void* const* d_in, const int* in_sizes, int n_in,
                              void* d_out, int out_size, void* d_ws, size_t ws_size,
                              hipStream_t stream) {
    const float* x = (const float*)d_in[0];
    const int* ei = (const int*)d_in[1];        // int32 [2, E]
    const float* Wl0 = (const float*)d_in[2];
    const float* b0  = (const float*)d_in[3];
    const float* Wr0 = (const float*)d_in[4];
    const float* Wl1 = (const float*)d_in[5];
    const float* b1  = (const float*)d_in[6];
    const float* Wr1 = (const float*)d_in[7];
    const float* Wl2 = (const float*)d_in[8];
    const float* b2  = (const float*)d_in[9];
    const float* Wr2 = (const float*)d_in[10];
    float* out = (float*)d_out;

    int eblocks = (N_EDGES + 255) / 256;
    int nblocks = (N_NODES + 255) / 256;   // 196

    zero_kernel<<<nblocks, 256, 0, stream>>>();
    deg_kernel<<<eblocks, 256, 0, stream>>>(ei);
    scan1_kernel<<<nblocks, 256, 0, stream>>>();
    scan2_kernel<<<1, 256, 0, stream>>>(nblocks);
    scan3_kernel<<<nblocks, 256, 0, stream>>>();
    fill_adj_kernel<<<eblocks, 256, 0, stream>>>(ei);

    // weight prep (split + transpose) + x -> bf16, tiny
    prep_w_kernel<<<128, 256, 0, stream>>>(Wl0, 128, 0);
    prep_w_kernel<<<128, 256, 0, stream>>>(Wr0, 128, 1);
    prep_w_kernel<<<256, 256, 0, stream>>>(Wl1, 256, 2);
    prep_w_kernel<<<256, 256, 0, stream>>>(Wr1, 256, 3);
    prep_w_kernel<<<256, 256, 0, stream>>>(Wl2, 256, 4);
    prep_w_kernel<<<256, 256, 0, stream>>>(Wr2, 256, 5);
    conv_x_kernel<<<(N_NODES * 128 / 4 + 255) / 256, 256, 0, stream>>>(x);

    int gblocks = (N_NODES + 63) / 64;   // 782

    // Layer 0: din=128   (agg <- bf16(x), root <- x, out -> g_hA + g_hbf)
    agg_bf_kernel<128><<<N_NODES, 128, 0, stream>>>();
    gemm2_mfma<128, true, true><<<gblocks, 256, 0, stream>>>(x, 0, 0, b0, nullptr, 0);

    // Layer 1: din=256   (agg <- bf16(hA), root <- g_hA, out -> g_hB + g_hbf)
    agg_bf_kernel<256><<<N_NODES, 256, 0, stream>>>();
    gemm2_mfma<256, true, true><<<gblocks, 256, 0, stream>>>(nullptr, 1, 2, b1, nullptr, 1);

    // Layer 2: din=256, no ReLU  (agg <- bf16(hB), root <- g_hB, out -> d_out)
    agg_bf_kernel<256><<<N_NODES, 256, 0, stream>>>();
    gemm2_mfma<256, false, false><<<gblocks, 256, 0, stream>>>(nullptr, 2, 4, b2, out, 2);
}

// Round 6
// 478.814 us; speedup vs baseline: 2.1102x; 1.2483x over previous
//
#include <hip/hip_runtime.h>
#include <hip/hip_bf16.h>

#define N_NODES 50000
#define N_EDGES 800000

typedef __attribute__((ext_vector_type(4))) float f32x4;
typedef __attribute__((ext_vector_type(16))) float f32x16;
typedef __attribute__((ext_vector_type(8))) short s16x8;

// ---------------------------------------------------------------------------
// Static device scratch
// ---------------------------------------------------------------------------
__device__ int   g_deg[N_NODES];
__device__ int   g_rowstart[N_NODES + 1];
__device__ int   g_cursor[N_NODES];
__device__ int   g_adj[N_EDGES];
__device__ int   g_bsum[256];
__device__ int   g_boff[256];
// bf16 feature buffers: aggregated neighbors, and layer-io ping-pong
__device__ __attribute__((aligned(256))) unsigned short g_aggbf[(size_t)N_NODES * 256];
__device__ __attribute__((aligned(256))) unsigned short g_bf0[(size_t)N_NODES * 256];
__device__ __attribute__((aligned(256))) unsigned short g_bf1[(size_t)N_NODES * 256];
// split-bf16 transposed weights: [matrix][n*K + k]
__device__ __attribute__((aligned(256))) unsigned short g_Whi[6][256 * 256];
__device__ __attribute__((aligned(256))) unsigned short g_Wlo[6][256 * 256];

__device__ __forceinline__ unsigned short f2bf(float f) {
    unsigned int u = __float_as_uint(f);
    unsigned int r = (u + 0x7fffu + ((u >> 16) & 1u)) >> 16;   // RNE
    return (unsigned short)r;
}
__device__ __forceinline__ float bf2f(unsigned short h) {
    return __uint_as_float(((unsigned int)h) << 16);
}

// ---------------------------------------------------------------------------
// CSR build: zero -> degree count -> 3-kernel scan -> atomic fill
// edge_index arrives as int32: [src[0..E-1], dst[0..E-1]]
// ---------------------------------------------------------------------------
__global__ void zero_kernel() {
    int i = blockIdx.x * blockDim.x + threadIdx.x;
    if (i < N_NODES) { g_deg[i] = 0; g_cursor[i] = 0; }
}

__global__ void deg_kernel(const int* __restrict__ ei) {
    int e = blockIdx.x * blockDim.x + threadIdx.x;
    if (e >= N_EDGES) return;
    int dst = ei[N_EDGES + e];
    if ((unsigned)dst < N_NODES) atomicAdd(&g_deg[dst], 1);
}

__global__ void scan1_kernel() {
    __shared__ int sm[256];
    int t = threadIdx.x;
    int idx = blockIdx.x * 256 + t;
    sm[t] = (idx < N_NODES) ? g_deg[idx] : 0;
    __syncthreads();
    for (int off = 128; off > 0; off >>= 1) {
        if (t < off) sm[t] += sm[t + off];
        __syncthreads();
    }
    if (t == 0) g_bsum[blockIdx.x] = sm[0];
}

__global__ void scan2_kernel(int nb) {
    __shared__ int sm[256];
    int t = threadIdx.x;
    int v = (t < nb) ? g_bsum[t] : 0;
    sm[t] = v;
    __syncthreads();
    for (int off = 1; off < 256; off <<= 1) {
        int tv = (t >= off) ? sm[t - off] : 0;
        __syncthreads();
        sm[t] += tv;
        __syncthreads();
    }
    g_boff[t] = sm[t] - v;                 // exclusive block offset
    if (t == nb - 1) g_rowstart[N_NODES] = sm[t];
}

__global__ void scan3_kernel() {
    __shared__ int sm[256];
    int t = threadIdx.x;
    int idx = blockIdx.x * 256 + t;
    int v = (idx < N_NODES) ? g_deg[idx] : 0;
    sm[t] = v;
    __syncthreads();
    for (int off = 1; off < 256; off <<= 1) {
        int tv = (t >= off) ? sm[t - off] : 0;
        __syncthreads();
        sm[t] += tv;
        __syncthreads();
    }
    if (idx < N_NODES) g_rowstart[idx] = g_boff[blockIdx.x] + sm[t] - v;
}

__global__ void fill_adj_kernel(const int* __restrict__ ei) {
    int e = blockIdx.x * blockDim.x + threadIdx.x;
    if (e >= N_EDGES) return;
    int src = ei[e];
    int dst = ei[N_EDGES + e];
    if ((unsigned)dst >= N_NODES) return;
    int p = atomicAdd(&g_cursor[dst], 1);
    int idx = g_rowstart[dst] + p;
    if ((unsigned)idx < N_EDGES)
        g_adj[idx] = ((unsigned)src < N_NODES) ? src : 0;
}

// ---------------------------------------------------------------------------
// Weight prep: W [K][256] fp32 -> transposed split bf16 Wt[n][k] (hi, lo)
// ---------------------------------------------------------------------------
__global__ void prep_w_kernel(const float* __restrict__ W, int K, int idx) {
    int e = blockIdx.x * 256 + threadIdx.x;
    if (e >= K * 256) return;
    int k = e >> 8, n = e & 255;
    float w = W[e];
    unsigned short hi = f2bf(w);
    unsigned short lo = f2bf(w - bf2f(hi));
    g_Whi[idx][n * K + k] = hi;
    g_Wlo[idx][n * K + k] = lo;
}

// x (N x 128 fp32) -> g_bf0 bf16
__global__ void conv_x_kernel(const float* __restrict__ x) {
    int i = blockIdx.x * 256 + threadIdx.x;   // quad index
    if (i >= N_NODES * 128 / 4) return;
    f32x4 v = *(const f32x4*)(x + (size_t)i * 4);
    unsigned long long p = (unsigned long long)f2bf(v.x)
                         | ((unsigned long long)f2bf(v.y) << 16)
                         | ((unsigned long long)f2bf(v.z) << 32)
                         | ((unsigned long long)f2bf(v.w) << 48);
    *(unsigned long long*)(g_bf0 + (size_t)i * 4) = p;
}

// ---------------------------------------------------------------------------
// Mean aggregation (bf16 gather -> bf16 out): one block/node, one thread/feat
// ---------------------------------------------------------------------------
template <int DIN>
__global__ __launch_bounds__(DIN) void agg_bf_kernel(int sel) {
    const unsigned short* __restrict__ hb = sel == 0 ? g_bf0 : g_bf1;
    int n = blockIdx.x;
    int t = threadIdx.x;
    int s = g_rowstart[n], e = g_rowstart[n + 1];
    float sum = 0.f;
    int i = s;
    for (; i + 8 <= e; i += 8) {
        int a0 = g_adj[i + 0], a1 = g_adj[i + 1], a2 = g_adj[i + 2], a3 = g_adj[i + 3];
        int a4 = g_adj[i + 4], a5 = g_adj[i + 5], a6 = g_adj[i + 6], a7 = g_adj[i + 7];
        unsigned short u0 = hb[(long)a0 * DIN + t];
        unsigned short u1 = hb[(long)a1 * DIN + t];
        unsigned short u2 = hb[(long)a2 * DIN + t];
        unsigned short u3 = hb[(long)a3 * DIN + t];
        unsigned short u4 = hb[(long)a4 * DIN + t];
        unsigned short u5 = hb[(long)a5 * DIN + t];
        unsigned short u6 = hb[(long)a6 * DIN + t];
        unsigned short u7 = hb[(long)a7 * DIN + t];
        sum += bf2f(u0) + bf2f(u1) + bf2f(u2) + bf2f(u3)
             + bf2f(u4) + bf2f(u5) + bf2f(u6) + bf2f(u7);
    }
    for (; i < e; ++i) sum += bf2f(hb[(long)g_adj[i] * DIN + t]);
    float cnt = (float)(e - s);
    g_aggbf[(long)n * DIN + t] = f2bf(sum / fmaxf(cnt, 1.0f));
}

// ---------------------------------------------------------------------------
// MFMA dual GEMM, pure-bf16 A, split-bf16 W (2 MFMA/frag):
//   out = aggbf @ W[widx] + bf[a2_sel] @ W[widx+1] + bias (+ReLU)
// Block 256 thr (4 waves). BM=256, BN=64, BK=64, mfma_f32_32x32x16_bf16.
// Wave w: rows w*64..+63 as 2x2 frags of 32x32. LDS rows 128B, XOR-swizzle
// byte ^= (row&7)<<4. LDS: A 32KB + Whi 8KB + Wlo 8KB = 48KB -> 3 blocks/CU.
// ---------------------------------------------------------------------------
template <int K, bool RELU, bool FP32OUT>
__global__ __launch_bounds__(256) void gemm2_mfma(
    int a2_sel, int widx, const float* __restrict__ bias,
    float* __restrict__ outp, int bfsel) {
    __shared__ __attribute__((aligned(16))) char lds[49152];
    char* const As = lds;            // 256 rows * 128B
    char* const Wh = lds + 32768;    // 64 rows * 128B
    char* const Wl = lds + 40960;    // 64 rows * 128B

    const int tid = threadIdx.x;
    const int w = tid >> 6;
    const int l = tid & 63;
    const int l31 = l & 31;
    const int lh = l >> 5;                 // 0/1
    const int bx = blockIdx.x;
    const int mblk = bx >> 2, nblk = bx & 3;
    const long row0 = (long)mblk * 256;
    const int ncol0 = nblk * 64;

    f32x16 acc[2][2];
#pragma unroll
    for (int i = 0; i < 2; ++i)
#pragma unroll
        for (int j = 0; j < 2; ++j) acc[i][j] = (f32x16)0.f;

    const int sar = tid >> 3;              // A stage: base row 0..31 (+j*32)
    const int sac = tid & 7;               // A stage: 16B chunk 0..7
    const int swn = tid >> 2;              // W stage: n-row 0..63
    const int swc = (tid & 3) * 2;         // W stage: chunk base

#pragma unroll
    for (int pass = 0; pass < 2; ++pass) {
        const unsigned short* A = pass ? (a2_sel == 0 ? (const unsigned short*)g_bf0
                                                      : (const unsigned short*)g_bf1)
                                       : (const unsigned short*)g_aggbf;
        const unsigned short* WH = g_Whi[widx + pass] + (long)ncol0 * K;
        const unsigned short* WL = g_Wlo[widx + pass] + (long)ncol0 * K;
        for (int kc = 0; kc < K; kc += 64) {
            __syncthreads();
            {   // stage A: 256 rows x 64 k bf16, 8 chunks/thread
#pragma unroll
                for (int j = 0; j < 8; ++j) {
                    int r = j * 32 + sar;
                    long grow = row0 + r; if (grow > N_NODES - 1) grow = N_NODES - 1;
                    s16x8 v = *(const s16x8*)(A + grow * K + kc + sac * 8);
                    *(s16x8*)(As + r * 128 + ((sac * 16) ^ ((r & 7) << 4))) = v;
                }
            }
            {   // stage W: 64 n-rows x 64 k bf16 (hi+lo), 2 chunks each/thread
#pragma unroll
                for (int q = 0; q < 2; ++q) {
                    int c = swc + q;
                    s16x8 vh = *(const s16x8*)(WH + (long)swn * K + kc + c * 8);
                    s16x8 vl = *(const s16x8*)(WL + (long)swn * K + kc + c * 8);
                    int o = swn * 128 + ((c * 16) ^ ((swn & 7) << 4));
                    *(s16x8*)(Wh + o) = vh;
                    *(s16x8*)(Wl + o) = vl;
                }
            }
            __syncthreads();
#pragma unroll
            for (int ks = 0; ks < 4; ++ks) {
                const int kb = ks * 32 + lh * 16;
                s16x8 af[2], bh[2], bl[2];
#pragma unroll
                for (int mi = 0; mi < 2; ++mi) {
                    int r = w * 64 + mi * 32 + l31;
                    af[mi] = *(const s16x8*)(As + r * 128 + (kb ^ ((r & 7) << 4)));
                }
#pragma unroll
                for (int ni = 0; ni < 2; ++ni) {
                    int n = ni * 32 + l31;
                    int o = n * 128 + (kb ^ ((n & 7) << 4));
                    bh[ni] = *(const s16x8*)(Wh + o);
                    bl[ni] = *(const s16x8*)(Wl + o);
                }
#pragma unroll
                for (int mi = 0; mi < 2; ++mi)
#pragma unroll
                    for (int ni = 0; ni < 2; ++ni)
                        acc[mi][ni] = __builtin_amdgcn_mfma_f32_32x32x16_bf16(af[mi], bh[ni], acc[mi][ni], 0, 0, 0);
#pragma unroll
                for (int mi = 0; mi < 2; ++mi)
#pragma unroll
                    for (int ni = 0; ni < 2; ++ni)
                        acc[mi][ni] = __builtin_amdgcn_mfma_f32_32x32x16_bf16(af[mi], bl[ni], acc[mi][ni], 0, 0, 0);
            }
        }
    }

    // epilogue: C/D layout col = lane&31, row = (reg&3)+8*(reg>>2)+4*(lane>>5)
    unsigned short* bfout = bfsel == 0 ? g_bf0 : g_bf1;
#pragma unroll
    for (int ni = 0; ni < 2; ++ni) {
        int col = ncol0 + ni * 32 + l31;
        float bv = bias[col];
#pragma unroll
        for (int mi = 0; mi < 2; ++mi) {
#pragma unroll
            for (int reg = 0; reg < 16; ++reg) {
                int lr = (reg & 3) + 8 * (reg >> 2) + 4 * lh;
                long grow = row0 + w * 64 + mi * 32 + lr;
                if (grow < N_NODES) {
                    float v = acc[mi][ni][reg] + bv;
                    if (RELU) v = fmaxf(v, 0.f);
                    if (FP32OUT) outp[grow * 256 + col] = v;
                    else bfout[grow * 256 + col] = f2bf(v);
                }
            }
        }
    }
}

// ---------------------------------------------------------------------------
extern "C" void kernel_launch(void* const* d_in, const int* in_sizes, int n_in,
                              void* d_out, int out_size, void* d_ws, size_t ws_size,
                              hipStream_t stream) {
    const float* x = (const float*)d_in[0];
    const int* ei = (const int*)d_in[1];        // int32 [2, E]
    const float* Wl0 = (const float*)d_in[2];
    const float* b0  = (const float*)d_in[3];
    const float* Wr0 = (const float*)d_in[4];
    const float* Wl1 = (const float*)d_in[5];
    const float* b1  = (const float*)d_in[6];
    const float* Wr1 = (const float*)d_in[7];
    const float* Wl2 = (const float*)d_in[8];
    const float* b2  = (const float*)d_in[9];
    const float* Wr2 = (const float*)d_in[10];
    float* out = (float*)d_out;

    int eblocks = (N_EDGES + 255) / 256;
    int nblocks = (N_NODES + 255) / 256;   // 196

    zero_kernel<<<nblocks, 256, 0, stream>>>();
    deg_kernel<<<eblocks, 256, 0, stream>>>(ei);
    scan1_kernel<<<nblocks, 256, 0, stream>>>();
    scan2_kernel<<<1, 256, 0, stream>>>(nblocks);
    scan3_kernel<<<nblocks, 256, 0, stream>>>();
    fill_adj_kernel<<<eblocks, 256, 0, stream>>>(ei);

    // weight prep (split + transpose) + x -> bf16, tiny
    prep_w_kernel<<<128, 256, 0, stream>>>(Wl0, 128, 0);
    prep_w_kernel<<<128, 256, 0, stream>>>(Wr0, 128, 1);
    prep_w_kernel<<<256, 256, 0, stream>>>(Wl1, 256, 2);
    prep_w_kernel<<<256, 256, 0, stream>>>(Wr1, 256, 3);
    prep_w_kernel<<<256, 256, 0, stream>>>(Wl2, 256, 4);
    prep_w_kernel<<<256, 256, 0, stream>>>(Wr2, 256, 5);
    conv_x_kernel<<<(N_NODES * 128 / 4 + 255) / 256, 256, 0, stream>>>(x);

    int gblocks = ((N_NODES + 255) / 256) * 4;   // 196 M-blocks x 4 N-blocks = 784

    // Layer 0: din=128   (agg <- g_bf0, root <- g_bf0, out -> g_bf1 bf16)
    agg_bf_kernel<128><<<N_NODES, 128, 0, stream>>>(0);
    gemm2_mfma<128, true, false><<<gblocks, 256, 0, stream>>>(0, 0, b0, nullptr, 1);

    // Layer 1: din=256   (agg <- g_bf1, root <- g_bf1, out -> g_bf0 bf16)
    agg_bf_kernel<256><<<N_NODES, 256, 0, stream>>>(1);
    gemm2_mfma<256, true, false><<<gblocks, 256, 0, stream>>>(1, 2, b1, nullptr, 0);

    // Layer 2: din=256, no ReLU  (agg <- g_bf0, root <- g_bf0, out -> d_out fp32)
    agg_bf_kernel<256><<<N_NODES, 256, 0, stream>>>(0);
    gemm2_mfma<256, false, true><<<gblocks, 256, 0, stream>>>(0, 4, b2, out, 0);
}

// Round 7
// 409.332 us; speedup vs baseline: 2.4684x; 1.1697x over previous
//
#include <hip/hip_runtime.h>
#include <hip/hip_bf16.h>

#define N_NODES 50000
#define N_EDGES 800000

typedef __attribute__((ext_vector_type(4))) float f32x4;
typedef __attribute__((ext_vector_type(16))) float f32x16;
typedef __attribute__((ext_vector_type(8))) short s16x8;

// ---------------------------------------------------------------------------
// Static device scratch
// ---------------------------------------------------------------------------
__device__ int   g_deg[N_NODES];
__device__ int   g_rowstart[N_NODES + 1];
__device__ int   g_cursor[N_NODES];
__device__ int   g_adj[N_EDGES];
__device__ int   g_bsum[256];
__device__ int   g_boff[256];
// bf16 feature buffers: aggregated neighbors, and layer-io ping-pong
__device__ __attribute__((aligned(256))) unsigned short g_aggbf[(size_t)N_NODES * 256];
__device__ __attribute__((aligned(256))) unsigned short g_bf0[(size_t)N_NODES * 256];
__device__ __attribute__((aligned(256))) unsigned short g_bf1[(size_t)N_NODES * 256];
// split-bf16 transposed weights: [matrix][n*K + k]
__device__ __attribute__((aligned(256))) unsigned short g_Whi[6][256 * 256];
__device__ __attribute__((aligned(256))) unsigned short g_Wlo[6][256 * 256];

__device__ __forceinline__ unsigned short f2bf(float f) {
    unsigned int u = __float_as_uint(f);
    unsigned int r = (u + 0x7fffu + ((u >> 16) & 1u)) >> 16;   // RNE
    return (unsigned short)r;
}
__device__ __forceinline__ float bf2f(unsigned short h) {
    return __uint_as_float(((unsigned int)h) << 16);
}

// ---------------------------------------------------------------------------
// CSR build: zero -> degree count -> 3-kernel scan -> atomic fill
// edge_index arrives as int32: [src[0..E-1], dst[0..E-1]]
// ---------------------------------------------------------------------------
__global__ void zero_kernel() {
    int i = blockIdx.x * blockDim.x + threadIdx.x;
    if (i < N_NODES) { g_deg[i] = 0; g_cursor[i] = 0; }
}

__global__ void deg_kernel(const int* __restrict__ ei) {
    int e = blockIdx.x * blockDim.x + threadIdx.x;
    if (e >= N_EDGES) return;
    int dst = ei[N_EDGES + e];
    if ((unsigned)dst < N_NODES) atomicAdd(&g_deg[dst], 1);
}

__global__ void scan1_kernel() {
    __shared__ int sm[256];
    int t = threadIdx.x;
    int idx = blockIdx.x * 256 + t;
    sm[t] = (idx < N_NODES) ? g_deg[idx] : 0;
    __syncthreads();
    for (int off = 128; off > 0; off >>= 1) {
        if (t < off) sm[t] += sm[t + off];
        __syncthreads();
    }
    if (t == 0) g_bsum[blockIdx.x] = sm[0];
}

__global__ void scan2_kernel(int nb) {
    __shared__ int sm[256];
    int t = threadIdx.x;
    int v = (t < nb) ? g_bsum[t] : 0;
    sm[t] = v;
    __syncthreads();
    for (int off = 1; off < 256; off <<= 1) {
        int tv = (t >= off) ? sm[t - off] : 0;
        __syncthreads();
        sm[t] += tv;
        __syncthreads();
    }
    g_boff[t] = sm[t] - v;                 // exclusive block offset
    if (t == nb - 1) g_rowstart[N_NODES] = sm[t];
}

__global__ void scan3_kernel() {
    __shared__ int sm[256];
    int t = threadIdx.x;
    int idx = blockIdx.x * 256 + t;
    int v = (idx < N_NODES) ? g_deg[idx] : 0;
    sm[t] = v;
    __syncthreads();
    for (int off = 1; off < 256; off <<= 1) {
        int tv = (t >= off) ? sm[t - off] : 0;
        __syncthreads();
        sm[t] += tv;
        __syncthreads();
    }
    if (idx < N_NODES) g_rowstart[idx] = g_boff[blockIdx.x] + sm[t] - v;
}

__global__ void fill_adj_kernel(const int* __restrict__ ei) {
    int e = blockIdx.x * blockDim.x + threadIdx.x;
    if (e >= N_EDGES) return;
    int src = ei[e];
    int dst = ei[N_EDGES + e];
    if ((unsigned)dst >= N_NODES) return;
    int p = atomicAdd(&g_cursor[dst], 1);
    int idx = g_rowstart[dst] + p;
    if ((unsigned)idx < N_EDGES)
        g_adj[idx] = ((unsigned)src < N_NODES) ? src : 0;
}

// ---------------------------------------------------------------------------
// Weight prep: W [K][256] fp32 -> transposed split bf16 Wt[n][k] (hi, lo)
// ---------------------------------------------------------------------------
__global__ void prep_w_kernel(const float* __restrict__ W, int K, int idx) {
    int e = blockIdx.x * 256 + threadIdx.x;
    if (e >= K * 256) return;
    int k = e >> 8, n = e & 255;
    float w = W[e];
    unsigned short hi = f2bf(w);
    unsigned short lo = f2bf(w - bf2f(hi));
    g_Whi[idx][n * K + k] = hi;
    g_Wlo[idx][n * K + k] = lo;
}

// x (N x 128 fp32) -> g_bf0 bf16
__global__ void conv_x_kernel(const float* __restrict__ x) {
    int i = blockIdx.x * 256 + threadIdx.x;   // quad index
    if (i >= N_NODES * 128 / 4) return;
    f32x4 v = *(const f32x4*)(x + (size_t)i * 4);
    unsigned long long p = (unsigned long long)f2bf(v.x)
                         | ((unsigned long long)f2bf(v.y) << 16)
                         | ((unsigned long long)f2bf(v.z) << 32)
                         | ((unsigned long long)f2bf(v.w) << 48);
    *(unsigned long long*)(g_bf0 + (size_t)i * 4) = p;
}

// ---------------------------------------------------------------------------
// Mean aggregation, one WAVE per destination node. Lane layout:
// LPR = DIN/8 lanes per source row, each lane loads 16B (8 bf16);
// RPW = 64/LPR rows processed per issue; 4-deep manual unroll.
// Cross-row-group reduce via __shfl_xor; fp32 accumulate; bf16 out.
// ---------------------------------------------------------------------------
template <int DIN>
__global__ __launch_bounds__(256) void agg_wave_kernel(int sel) {
    const unsigned short* __restrict__ hb = sel == 0 ? g_bf0 : g_bf1;
    constexpr int LPR = DIN / 8;          // 16 (DIN=128) or 32 (DIN=256)
    constexpr int RPW = 64 / LPR;         // 4 or 2
    const int node = blockIdx.x * 4 + (threadIdx.x >> 6);
    if (node >= N_NODES) return;
    const int lane = threadIdx.x & 63;
    const int rg = lane / LPR;            // row-group
    const int cl = lane % LPR;            // column-lane (8 feats each)
    const int s = g_rowstart[node], e = g_rowstart[node + 1];

    float acc[8];
#pragma unroll
    for (int j = 0; j < 8; ++j) acc[j] = 0.f;

    int i = s;
    for (; i + 4 * RPW <= e; i += 4 * RPW) {
        int a0 = g_adj[i + 0 * RPW + rg];
        int a1 = g_adj[i + 1 * RPW + rg];
        int a2 = g_adj[i + 2 * RPW + rg];
        int a3 = g_adj[i + 3 * RPW + rg];
        s16x8 v0 = *(const s16x8*)(hb + (long)a0 * DIN + cl * 8);
        s16x8 v1 = *(const s16x8*)(hb + (long)a1 * DIN + cl * 8);
        s16x8 v2 = *(const s16x8*)(hb + (long)a2 * DIN + cl * 8);
        s16x8 v3 = *(const s16x8*)(hb + (long)a3 * DIN + cl * 8);
#pragma unroll
        for (int j = 0; j < 8; ++j)
            acc[j] += bf2f((unsigned short)v0[j]) + bf2f((unsigned short)v1[j])
                    + bf2f((unsigned short)v2[j]) + bf2f((unsigned short)v3[j]);
    }
    for (; i < e; i += RPW) {
        int eidx = i + rg;
        if (eidx < e) {
            int a = g_adj[eidx];
            s16x8 v = *(const s16x8*)(hb + (long)a * DIN + cl * 8);
#pragma unroll
            for (int j = 0; j < 8; ++j) acc[j] += bf2f((unsigned short)v[j]);
        }
    }

    // reduce across row-groups (lanes sharing cl)
#pragma unroll
    for (int j = 0; j < 8; ++j) {
        if (RPW == 4) acc[j] += __shfl_xor(acc[j], 16, 64);
        acc[j] += __shfl_xor(acc[j], 32, 64);
    }

    if (rg == 0) {
        float inv = 1.f / fmaxf((float)(e - s), 1.f);
        s16x8 ov;
#pragma unroll
        for (int j = 0; j < 8; ++j) ov[j] = (short)f2bf(acc[j] * inv);
        *(s16x8*)(g_aggbf + (long)node * DIN + cl * 8) = ov;
    }
}

// ---------------------------------------------------------------------------
// MFMA dual GEMM, pure-bf16 A, split-bf16 W (2 MFMA/frag):
//   out = aggbf @ W[widx] + bf[a2_sel] @ W[widx+1] + bias (+ReLU)
// Block 256 thr (4 waves). BM=256, BN=64, BK=64, mfma_f32_32x32x16_bf16.
// Wave w: rows w*64..+63 as 2x2 frags of 32x32. LDS rows 128B, XOR-swizzle
// byte ^= (row&7)<<4. LDS: A 32KB + Whi 8KB + Wlo 8KB = 48KB -> 3 blocks/CU.
// ---------------------------------------------------------------------------
template <int K, bool RELU, bool FP32OUT>
__global__ __launch_bounds__(256) void gemm2_mfma(
    int a2_sel, int widx, const float* __restrict__ bias,
    float* __restrict__ outp, int bfsel) {
    __shared__ __attribute__((aligned(16))) char lds[49152];
    char* const As = lds;            // 256 rows * 128B
    char* const Wh = lds + 32768;    // 64 rows * 128B
    char* const Wl = lds + 40960;    // 64 rows * 128B

    const int tid = threadIdx.x;
    const int w = tid >> 6;
    const int l = tid & 63;
    const int l31 = l & 31;
    const int lh = l >> 5;                 // 0/1
    const int bx = blockIdx.x;
    const int mblk = bx >> 2, nblk = bx & 3;
    const long row0 = (long)mblk * 256;
    const int ncol0 = nblk * 64;

    f32x16 acc[2][2];
#pragma unroll
    for (int i = 0; i < 2; ++i)
#pragma unroll
        for (int j = 0; j < 2; ++j) acc[i][j] = (f32x16)0.f;

    const int sar = tid >> 3;              // A stage: base row 0..31 (+j*32)
    const int sac = tid & 7;               // A stage: 16B chunk 0..7
    const int swn = tid >> 2;              // W stage: n-row 0..63
    const int swc = (tid & 3) * 2;         // W stage: chunk base

#pragma unroll
    for (int pass = 0; pass < 2; ++pass) {
        const unsigned short* A = pass ? (a2_sel == 0 ? (const unsigned short*)g_bf0
                                                      : (const unsigned short*)g_bf1)
                                       : (const unsigned short*)g_aggbf;
        const unsigned short* WH = g_Whi[widx + pass] + (long)ncol0 * K;
        const unsigned short* WL = g_Wlo[widx + pass] + (long)ncol0 * K;
        for (int kc = 0; kc < K; kc += 64) {
            __syncthreads();
            {   // stage A: 256 rows x 64 k bf16, 8 chunks/thread
#pragma unroll
                for (int j = 0; j < 8; ++j) {
                    int r = j * 32 + sar;
                    long grow = row0 + r; if (grow > N_NODES - 1) grow = N_NODES - 1;
                    s16x8 v = *(const s16x8*)(A + grow * K + kc + sac * 8);
                    *(s16x8*)(As + r * 128 + ((sac * 16) ^ ((r & 7) << 4))) = v;
                }
            }
            {   // stage W: 64 n-rows x 64 k bf16 (hi+lo), 2 chunks each/thread
#pragma unroll
                for (int q = 0; q < 2; ++q) {
                    int c = swc + q;
                    s16x8 vh = *(const s16x8*)(WH + (long)swn * K + kc + c * 8);
                    s16x8 vl = *(const s16x8*)(WL + (long)swn * K + kc + c * 8);
                    int o = swn * 128 + ((c * 16) ^ ((swn & 7) << 4));
                    *(s16x8*)(Wh + o) = vh;
                    *(s16x8*)(Wl + o) = vl;
                }
            }
            __syncthreads();
#pragma unroll
            for (int ks = 0; ks < 4; ++ks) {
                const int kb = ks * 32 + lh * 16;
                s16x8 af[2], bh[2], bl[2];
#pragma unroll
                for (int mi = 0; mi < 2; ++mi) {
                    int r = w * 64 + mi * 32 + l31;
                    af[mi] = *(const s16x8*)(As + r * 128 + (kb ^ ((r & 7) << 4)));
                }
#pragma unroll
                for (int ni = 0; ni < 2; ++ni) {
                    int n = ni * 32 + l31;
                    int o = n * 128 + (kb ^ ((n & 7) << 4));
                    bh[ni] = *(const s16x8*)(Wh + o);
                    bl[ni] = *(const s16x8*)(Wl + o);
                }
#pragma unroll
                for (int mi = 0; mi < 2; ++mi)
#pragma unroll
                    for (int ni = 0; ni < 2; ++ni)
                        acc[mi][ni] = __builtin_amdgcn_mfma_f32_32x32x16_bf16(af[mi], bh[ni], acc[mi][ni], 0, 0, 0);
#pragma unroll
                for (int mi = 0; mi < 2; ++mi)
#pragma unroll
                    for (int ni = 0; ni < 2; ++ni)
                        acc[mi][ni] = __builtin_amdgcn_mfma_f32_32x32x16_bf16(af[mi], bl[ni], acc[mi][ni], 0, 0, 0);
            }
        }
    }

    // epilogue: C/D layout col = lane&31, row = (reg&3)+8*(reg>>2)+4*(lane>>5)
    unsigned short* bfout = bfsel == 0 ? g_bf0 : g_bf1;
#pragma unroll
    for (int ni = 0; ni < 2; ++ni) {
        int col = ncol0 + ni * 32 + l31;
        float bv = bias[col];
#pragma unroll
        for (int mi = 0; mi < 2; ++mi) {
#pragma unroll
            for (int reg = 0; reg < 16; ++reg) {
                int lr = (reg & 3) + 8 * (reg >> 2) + 4 * lh;
                long grow = row0 + w * 64 + mi * 32 + lr;
                if (grow < N_NODES) {
                    float v = acc[mi][ni][reg] + bv;
                    if (RELU) v = fmaxf(v, 0.f);
                    if (FP32OUT) outp[grow * 256 + col] = v;
                    else bfout[grow * 256 + col] = f2bf(v);
                }
            }
        }
    }
}

// ---------------------------------------------------------------------------
extern "C" void kernel_launch(void* const* d_in, const int* in_sizes, int n_in,
                              void* d_out, int out_size, void* d_ws, size_t ws_size,
                              hipStream_t stream) {
    const float* x = (const float*)d_in[0];
    const int* ei = (const int*)d_in[1];        // int32 [2, E]
    const float* Wl0 = (const float*)d_in[2];
    const float* b0  = (const float*)d_in[3];
    const float* Wr0 = (const float*)d_in[4];
    const float* Wl1 = (const float*)d_in[5];
    const float* b1  = (const float*)d_in[6];
    const float* Wr1 = (const float*)d_in[7];
    const float* Wl2 = (const float*)d_in[8];
    const float* b2  = (const float*)d_in[9];
    const float* Wr2 = (const float*)d_in[10];
    float* out = (float*)d_out;

    int eblocks = (N_EDGES + 255) / 256;
    int nblocks = (N_NODES + 255) / 256;   // 196

    zero_kernel<<<nblocks, 256, 0, stream>>>();
    deg_kernel<<<eblocks, 256, 0, stream>>>(ei);
    scan1_kernel<<<nblocks, 256, 0, stream>>>();
    scan2_kernel<<<1, 256, 0, stream>>>(nblocks);
    scan3_kernel<<<nblocks, 256, 0, stream>>>();
    fill_adj_kernel<<<eblocks, 256, 0, stream>>>(ei);

    // weight prep (split + transpose) + x -> bf16, tiny
    prep_w_kernel<<<128, 256, 0, stream>>>(Wl0, 128, 0);
    prep_w_kernel<<<128, 256, 0, stream>>>(Wr0, 128, 1);
    prep_w_kernel<<<256, 256, 0, stream>>>(Wl1, 256, 2);
    prep_w_kernel<<<256, 256, 0, stream>>>(Wr1, 256, 3);
    prep_w_kernel<<<256, 256, 0, stream>>>(Wl2, 256, 4);
    prep_w_kernel<<<256, 256, 0, stream>>>(Wr2, 256, 5);
    conv_x_kernel<<<(N_NODES * 128 / 4 + 255) / 256, 256, 0, stream>>>(x);

    int gblocks = ((N_NODES + 255) / 256) * 4;   // 196 M-blocks x 4 N-blocks = 784
    int ablocks = (N_NODES + 3) / 4;             // 12500 (4 waves/block, 1 node/wave)

    // Layer 0: din=128   (agg <- g_bf0, root <- g_bf0, out -> g_bf1 bf16)
    agg_wave_kernel<128><<<ablocks, 256, 0, stream>>>(0);
    gemm2_mfma<128, true, false><<<gblocks, 256, 0, stream>>>(0, 0, b0, nullptr, 1);

    // Layer 1: din=256   (agg <- g_bf1, root <- g_bf1, out -> g_bf0 bf16)
    agg_wave_kernel<256><<<ablocks, 256, 0, stream>>>(1);
    gemm2_mfma<256, true, false><<<gblocks, 256, 0, stream>>>(1, 2, b1, nullptr, 0);

    // Layer 2: din=256, no ReLU  (agg <- g_bf0, root <- g_bf0, out -> d_out fp32)
    agg_wave_kernel<256><<<ablocks, 256, 0, stream>>>(0);
    gemm2_mfma<256, false, true><<<gblocks, 256, 0, stream>>>(0, 4, b2, out, 2);
}

// Round 8
// 380.329 us; speedup vs baseline: 2.6567x; 1.0763x over previous
//
#include <hip/hip_runtime.h>
#include <hip/hip_bf16.h>

#define N_NODES 50000
#define N_EDGES 800000
#define MBLKS ((N_NODES + 255) / 256)   // 196

typedef __attribute__((ext_vector_type(4))) float f32x4;
typedef __attribute__((ext_vector_type(16))) float f32x16;
typedef __attribute__((ext_vector_type(8))) short s16x8;

// ---------------------------------------------------------------------------
// Static device scratch
// ---------------------------------------------------------------------------
__device__ int   g_deg[N_NODES];
__device__ int   g_rowstart[N_NODES + 1];
__device__ int   g_cursor[N_NODES];
__device__ int   g_adj[N_EDGES];
__device__ int   g_bsum[256];
__device__ int   g_boff[256];
// bf16 feature buffers: aggregated neighbors, and layer-io ping-pong
__device__ __attribute__((aligned(256))) unsigned short g_aggbf[(size_t)N_NODES * 256];
__device__ __attribute__((aligned(256))) unsigned short g_bf0[(size_t)N_NODES * 256];
__device__ __attribute__((aligned(256))) unsigned short g_bf1[(size_t)N_NODES * 256];
// split-bf16 transposed weights: [matrix][n*K + k]
__device__ __attribute__((aligned(256))) unsigned short g_Whi[6][256 * 256];
__device__ __attribute__((aligned(256))) unsigned short g_Wlo[6][256 * 256];

__device__ __forceinline__ unsigned short f2bf(float f) {
    unsigned int u = __float_as_uint(f);
    unsigned int r = (u + 0x7fffu + ((u >> 16) & 1u)) >> 16;   // RNE
    return (unsigned short)r;
}
__device__ __forceinline__ float bf2f(unsigned short h) {
    return __uint_as_float(((unsigned int)h) << 16);
}

// ---------------------------------------------------------------------------
// CSR build: zero -> degree count -> 3-kernel scan -> atomic fill
// edge_index arrives as int32: [src[0..E-1], dst[0..E-1]]
// ---------------------------------------------------------------------------
__global__ void zero_kernel() {
    int i = blockIdx.x * blockDim.x + threadIdx.x;
    if (i < N_NODES) { g_deg[i] = 0; g_cursor[i] = 0; }
}

__global__ void deg_kernel(const int* __restrict__ ei) {
    int e = blockIdx.x * blockDim.x + threadIdx.x;
    if (e >= N_EDGES) return;
    int dst = ei[N_EDGES + e];
    if ((unsigned)dst < N_NODES) atomicAdd(&g_deg[dst], 1);
}

__global__ void scan1_kernel() {
    __shared__ int sm[256];
    int t = threadIdx.x;
    int idx = blockIdx.x * 256 + t;
    sm[t] = (idx < N_NODES) ? g_deg[idx] : 0;
    __syncthreads();
    for (int off = 128; off > 0; off >>= 1) {
        if (t < off) sm[t] += sm[t + off];
        __syncthreads();
    }
    if (t == 0) g_bsum[blockIdx.x] = sm[0];
}

__global__ void scan2_kernel(int nb) {
    __shared__ int sm[256];
    int t = threadIdx.x;
    int v = (t < nb) ? g_bsum[t] : 0;
    sm[t] = v;
    __syncthreads();
    for (int off = 1; off < 256; off <<= 1) {
        int tv = (t >= off) ? sm[t - off] : 0;
        __syncthreads();
        sm[t] += tv;
        __syncthreads();
    }
    g_boff[t] = sm[t] - v;                 // exclusive block offset
    if (t == nb - 1) g_rowstart[N_NODES] = sm[t];
}

__global__ void scan3_kernel() {
    __shared__ int sm[256];
    int t = threadIdx.x;
    int idx = blockIdx.x * 256 + t;
    int v = (idx < N_NODES) ? g_deg[idx] : 0;
    sm[t] = v;
    __syncthreads();
    for (int off = 1; off < 256; off <<= 1) {
        int tv = (t >= off) ? sm[t - off] : 0;
        __syncthreads();
        sm[t] += tv;
        __syncthreads();
    }
    if (idx < N_NODES) g_rowstart[idx] = g_boff[blockIdx.x] + sm[t] - v;
}

__global__ void fill_adj_kernel(const int* __restrict__ ei) {
    int e = blockIdx.x * blockDim.x + threadIdx.x;
    if (e >= N_EDGES) return;
    int src = ei[e];
    int dst = ei[N_EDGES + e];
    if ((unsigned)dst >= N_NODES) return;
    int p = atomicAdd(&g_cursor[dst], 1);
    int idx = g_rowstart[dst] + p;
    if ((unsigned)idx < N_EDGES)
        g_adj[idx] = ((unsigned)src < N_NODES) ? src : 0;
}

// ---------------------------------------------------------------------------
// Merged prep: segments for 6 weight matrices (split+transpose) + x->bf16.
// Segment layout (block index): [0,128) Wl0; [128,256) Wr0; [256,512) Wl1;
// [512,768) Wr1; [768,1024) Wl2; [1024,1280) Wr2; [1280,1280+3125) conv x.
// ---------------------------------------------------------------------------
__device__ __forceinline__ void prep_w_seg(const float* __restrict__ W, int K,
                                           int widx, int lbx, int tid) {
    int e = lbx * 256 + tid;
    if (e >= K * 256) return;
    int k = e >> 8, n = e & 255;
    float w = W[e];
    unsigned short hi = f2bf(w);
    unsigned short lo = f2bf(w - bf2f(hi));
    g_Whi[widx][n * K + k] = hi;
    g_Wlo[widx][n * K + k] = lo;
}

__global__ void prep_all_kernel(const float* __restrict__ x,
                                const float* __restrict__ Wl0, const float* __restrict__ Wr0,
                                const float* __restrict__ Wl1, const float* __restrict__ Wr1,
                                const float* __restrict__ Wl2, const float* __restrict__ Wr2) {
    int bx = blockIdx.x;
    int tid = threadIdx.x;
    if (bx < 128)        { prep_w_seg(Wl0, 128, 0, bx, tid);        return; }
    if (bx < 256)        { prep_w_seg(Wr0, 128, 1, bx - 128, tid);  return; }
    if (bx < 512)        { prep_w_seg(Wl1, 256, 2, bx - 256, tid);  return; }
    if (bx < 768)        { prep_w_seg(Wr1, 256, 3, bx - 512, tid);  return; }
    if (bx < 1024)       { prep_w_seg(Wl2, 256, 4, bx - 768, tid);  return; }
    if (bx < 1280)       { prep_w_seg(Wr2, 256, 5, bx - 1024, tid); return; }
    // conv x: 8 floats per thread
    long i = (long)(bx - 1280) * 256 + tid;       // oct index
    if (i >= (long)N_NODES * 128 / 8) return;
    const float* xp = x + i * 8;
    f32x4 v0 = *(const f32x4*)(xp);
    f32x4 v1 = *(const f32x4*)(xp + 4);
    s16x8 o;
    o[0] = (short)f2bf(v0.x); o[1] = (short)f2bf(v0.y);
    o[2] = (short)f2bf(v0.z); o[3] = (short)f2bf(v0.w);
    o[4] = (short)f2bf(v1.x); o[5] = (short)f2bf(v1.y);
    o[6] = (short)f2bf(v1.z); o[7] = (short)f2bf(v1.w);
    *(s16x8*)(g_bf0 + i * 8) = o;
}

// ---------------------------------------------------------------------------
// Mean aggregation, one WAVE per destination node. Lane layout:
// LPR = DIN/8 lanes per source row, each lane loads 16B (8 bf16);
// RPW = 64/LPR rows processed per issue; 4-deep manual unroll.
// ---------------------------------------------------------------------------
template <int DIN>
__global__ __launch_bounds__(256) void agg_wave_kernel(int sel) {
    const unsigned short* __restrict__ hb = sel == 0 ? g_bf0 : g_bf1;
    constexpr int LPR = DIN / 8;          // 16 (DIN=128) or 32 (DIN=256)
    constexpr int RPW = 64 / LPR;         // 4 or 2
    const int node = blockIdx.x * 4 + (threadIdx.x >> 6);
    if (node >= N_NODES) return;
    const int lane = threadIdx.x & 63;
    const int rg = lane / LPR;            // row-group
    const int cl = lane % LPR;            // column-lane (8 feats each)
    const int s = g_rowstart[node], e = g_rowstart[node + 1];

    float acc[8];
#pragma unroll
    for (int j = 0; j < 8; ++j) acc[j] = 0.f;

    int i = s;
    for (; i + 4 * RPW <= e; i += 4 * RPW) {
        int a0 = g_adj[i + 0 * RPW + rg];
        int a1 = g_adj[i + 1 * RPW + rg];
        int a2 = g_adj[i + 2 * RPW + rg];
        int a3 = g_adj[i + 3 * RPW + rg];
        s16x8 v0 = *(const s16x8*)(hb + (long)a0 * DIN + cl * 8);
        s16x8 v1 = *(const s16x8*)(hb + (long)a1 * DIN + cl * 8);
        s16x8 v2 = *(const s16x8*)(hb + (long)a2 * DIN + cl * 8);
        s16x8 v3 = *(const s16x8*)(hb + (long)a3 * DIN + cl * 8);
#pragma unroll
        for (int j = 0; j < 8; ++j)
            acc[j] += bf2f((unsigned short)v0[j]) + bf2f((unsigned short)v1[j])
                    + bf2f((unsigned short)v2[j]) + bf2f((unsigned short)v3[j]);
    }
    for (; i < e; i += RPW) {
        int eidx = i + rg;
        if (eidx < e) {
            int a = g_adj[eidx];
            s16x8 v = *(const s16x8*)(hb + (long)a * DIN + cl * 8);
#pragma unroll
            for (int j = 0; j < 8; ++j) acc[j] += bf2f((unsigned short)v[j]);
        }
    }

#pragma unroll
    for (int j = 0; j < 8; ++j) {
        if (RPW == 4) acc[j] += __shfl_xor(acc[j], 16, 64);
        acc[j] += __shfl_xor(acc[j], 32, 64);
    }

    if (rg == 0) {
        float inv = 1.f / fmaxf((float)(e - s), 1.f);
        s16x8 ov;
#pragma unroll
        for (int j = 0; j < 8; ++j) ov[j] = (short)f2bf(acc[j] * inv);
        *(s16x8*)(g_aggbf + (long)node * DIN + cl * 8) = ov;
    }
}

// ---------------------------------------------------------------------------
// MFMA dual GEMM, pure-bf16 A, split-bf16 W (2 MFMA/frag):
//   out = aggbf @ W[widx] + bf[a2_sel] @ W[widx+1] + bias (+ReLU)
// Block 256 thr (4 waves). BM=256, BN=64, BK=64, mfma_f32_32x32x16_bf16.
// XCD-aware bijective mapping: grid 800 = 8 xcd x 25 mloc x 4 nblk; all 4
// N-blocks of an M-tile land on one XCD (shared A panel in that L2).
// T14 prefetch: issue next K-step's global loads right after barrier1,
// ds_write them at next loop top (latency hides under 32 MFMAs).
// LDS rows 128B, XOR-swizzle byte ^= (row&7)<<4. 48KB -> 3 blocks/CU.
// ---------------------------------------------------------------------------
template <int K, bool RELU, bool FP32OUT>
__global__ __launch_bounds__(256, 3) void gemm2_mfma(
    int a2_sel, int widx, const float* __restrict__ bias,
    float* __restrict__ outp, int bfsel) {
    __shared__ __attribute__((aligned(16))) char lds[49152];
    char* const As = lds;            // 256 rows * 128B
    char* const Wh = lds + 32768;    // 64 rows * 128B
    char* const Wl = lds + 40960;    // 64 rows * 128B

    const int tid = threadIdx.x;
    const int w = tid >> 6;
    const int l = tid & 63;
    const int l31 = l & 31;
    const int lh = l >> 5;                 // 0/1
    // XCD-aware mapping (8 XCDs, round-robin bx%8)
    const int bx = blockIdx.x;
    const int xcd = bx & 7;
    const int idx = bx >> 3;               // 0..99
    const int mblk = (idx >> 2) * 8 + xcd; // 0..199
    const int nblk = idx & 3;
    if (mblk >= MBLKS) return;
    const long row0 = (long)mblk * 256;
    const int ncol0 = nblk * 64;

    f32x16 acc[2][2];
#pragma unroll
    for (int i = 0; i < 2; ++i)
#pragma unroll
        for (int j = 0; j < 2; ++j) acc[i][j] = (f32x16)0.f;

    const int sar = tid >> 3;              // A stage: base row 0..31 (+j*32)
    const int sac = tid & 7;               // A stage: 16B chunk 0..7
    const int swn = tid >> 2;              // W stage: n-row 0..63
    const int swc = (tid & 3) * 2;         // W stage: chunk base

    const unsigned short* A2p = a2_sel == 0 ? (const unsigned short*)g_bf0
                                            : (const unsigned short*)g_bf1;
    constexpr int NPP = K / 64;            // K-steps per pass
    constexpr int NT = NPP * 2;            // total steps (2 passes)

    s16x8 aR[8], whR[2], wlR[2];
    auto issue = [&](int t) {
        int pass = (t >= NPP) ? 1 : 0;
        int kc = (t - pass * NPP) * 64;
        const unsigned short* A = pass ? A2p : (const unsigned short*)g_aggbf;
        const unsigned short* WH = g_Whi[widx + pass] + (long)ncol0 * K;
        const unsigned short* WL = g_Wlo[widx + pass] + (long)ncol0 * K;
#pragma unroll
        for (int j = 0; j < 8; ++j) {
            int r = j * 32 + sar;
            long grow = row0 + r; if (grow > N_NODES - 1) grow = N_NODES - 1;
            aR[j] = *(const s16x8*)(A + grow * K + kc + sac * 8);
        }
#pragma unroll
        for (int q = 0; q < 2; ++q) {
            int c = swc + q;
            whR[q] = *(const s16x8*)(WH + (long)swn * K + kc + c * 8);
            wlR[q] = *(const s16x8*)(WL + (long)swn * K + kc + c * 8);
        }
    };

    issue(0);
    for (int t = 0; t < NT; ++t) {
        // write staged regs -> LDS (waits the global loads)
#pragma unroll
        for (int j = 0; j < 8; ++j) {
            int r = j * 32 + sar;
            *(s16x8*)(As + r * 128 + ((sac * 16) ^ ((r & 7) << 4))) = aR[j];
        }
#pragma unroll
        for (int q = 0; q < 2; ++q) {
            int c = swc + q;
            int o = swn * 128 + ((c * 16) ^ ((swn & 7) << 4));
            *(s16x8*)(Wh + o) = whR[q];
            *(s16x8*)(Wl + o) = wlR[q];
        }
        __syncthreads();
        if (t + 1 < NT) issue(t + 1);     // prefetch next step (T14)
#pragma unroll
        for (int ks = 0; ks < 4; ++ks) {
            const int kb = ks * 32 + lh * 16;
            s16x8 af[2], bh[2], bl[2];
#pragma unroll
            for (int mi = 0; mi < 2; ++mi) {
                int r = w * 64 + mi * 32 + l31;
                af[mi] = *(const s16x8*)(As + r * 128 + (kb ^ ((r & 7) << 4)));
            }
#pragma unroll
            for (int ni = 0; ni < 2; ++ni) {
                int n = ni * 32 + l31;
                int o = n * 128 + (kb ^ ((n & 7) << 4));
                bh[ni] = *(const s16x8*)(Wh + o);
                bl[ni] = *(const s16x8*)(Wl + o);
            }
#pragma unroll
            for (int mi = 0; mi < 2; ++mi)
#pragma unroll
                for (int ni = 0; ni < 2; ++ni)
                    acc[mi][ni] = __builtin_amdgcn_mfma_f32_32x32x16_bf16(af[mi], bh[ni], acc[mi][ni], 0, 0, 0);
#pragma unroll
            for (int mi = 0; mi < 2; ++mi)
#pragma unroll
                for (int ni = 0; ni < 2; ++ni)
                    acc[mi][ni] = __builtin_amdgcn_mfma_f32_32x32x16_bf16(af[mi], bl[ni], acc[mi][ni], 0, 0, 0);
        }
        __syncthreads();
    }

    // epilogue: C/D layout col = lane&31, row = (reg&3)+8*(reg>>2)+4*(lane>>5)
    unsigned short* bfout = bfsel == 0 ? g_bf0 : g_bf1;
#pragma unroll
    for (int ni = 0; ni < 2; ++ni) {
        int col = ncol0 + ni * 32 + l31;
        float bv = bias[col];
#pragma unroll
        for (int mi = 0; mi < 2; ++mi) {
#pragma unroll
            for (int reg = 0; reg < 16; ++reg) {
                int lr = (reg & 3) + 8 * (reg >> 2) + 4 * lh;
                long grow = row0 + w * 64 + mi * 32 + lr;
                if (grow < N_NODES) {
                    float v = acc[mi][ni][reg] + bv;
                    if (RELU) v = fmaxf(v, 0.f);
                    if (FP32OUT) outp[grow * 256 + col] = v;
                    else bfout[grow * 256 + col] = f2bf(v);
                }
            }
        }
    }
}

// ---------------------------------------------------------------------------
extern "C" void kernel_launch(void* const* d_in, const int* in_sizes, int n_in,
                              void* d_out, int out_size, void* d_ws, size_t ws_size,
                              hipStream_t stream) {
    const float* x = (const float*)d_in[0];
    const int* ei = (const int*)d_in[1];        // int32 [2, E]
    const float* Wl0 = (const float*)d_in[2];
    const float* b0  = (const float*)d_in[3];
    const float* Wr0 = (const float*)d_in[4];
    const float* Wl1 = (const float*)d_in[5];
    const float* b1  = (const float*)d_in[6];
    const float* Wr1 = (const float*)d_in[7];
    const float* Wl2 = (const float*)d_in[8];
    const float* b2  = (const float*)d_in[9];
    const float* Wr2 = (const float*)d_in[10];
    float* out = (float*)d_out;

    int eblocks = (N_EDGES + 255) / 256;
    int nblocks = (N_NODES + 255) / 256;   // 196

    zero_kernel<<<nblocks, 256, 0, stream>>>();
    deg_kernel<<<eblocks, 256, 0, stream>>>(ei);
    scan1_kernel<<<nblocks, 256, 0, stream>>>();
    scan2_kernel<<<1, 256, 0, stream>>>(nblocks);
    scan3_kernel<<<nblocks, 256, 0, stream>>>();
    fill_adj_kernel<<<eblocks, 256, 0, stream>>>(ei);

    // merged weight prep + x->bf16: 1280 W-blocks + 3125 conv-blocks
    prep_all_kernel<<<1280 + 3125, 256, 0, stream>>>(x, Wl0, Wr0, Wl1, Wr1, Wl2, Wr2);

    int gblocks = 800;                    // 8 xcd x 25 mloc x 4 nblk
    int ablocks = (N_NODES + 3) / 4;      // 12500 (4 waves/block, 1 node/wave)

    // Layer 0: din=128   (agg <- g_bf0, root <- g_bf0, out -> g_bf1 bf16)
    agg_wave_kernel<128><<<ablocks, 256, 0, stream>>>(0);
    gemm2_mfma<128, true, false><<<gblocks, 256, 0, stream>>>(0, 0, b0, nullptr, 1);

    // Layer 1: din=256   (agg <- g_bf1, root <- g_bf1, out -> g_bf0 bf16)
    agg_wave_kernel<256><<<ablocks, 256, 0, stream>>>(1);
    gemm2_mfma<256, true, false><<<gblocks, 256, 0, stream>>>(1, 2, b1, nullptr, 0);

    // Layer 2: din=256, no ReLU  (agg <- g_bf0, root <- g_bf0, out -> d_out fp32)
    agg_wave_kernel<256><<<ablocks, 256, 0, stream>>>(0);
    gemm2_mfma<256, false, true><<<gblocks, 256, 0, stream>>>(0, 4, b2, out, 1);
}

// Round 9
// 372.763 us; speedup vs baseline: 2.7106x; 1.0203x over previous
//
#include <hip/hip_runtime.h>
#include <hip/hip_bf16.h>

#define N_NODES 50000
#define N_EDGES 800000
#define MBLKS ((N_NODES + 255) / 256)   // 196

typedef __attribute__((ext_vector_type(4))) float f32x4;
typedef __attribute__((ext_vector_type(16))) float f32x16;
typedef __attribute__((ext_vector_type(8))) short s16x8;

// ---------------------------------------------------------------------------
// Static device scratch
// ---------------------------------------------------------------------------
__device__ int   g_deg[N_NODES];
__device__ int   g_rowstart[N_NODES + 1];
__device__ int   g_cursor[N_NODES];
__device__ int   g_adj[N_EDGES];
__device__ int   g_bsum[256];
__device__ int   g_boff[256];
// bf16 feature buffers: aggregated neighbors, and layer-io ping-pong
__device__ __attribute__((aligned(256))) unsigned short g_aggbf[(size_t)N_NODES * 256];
__device__ __attribute__((aligned(256))) unsigned short g_bf0[(size_t)N_NODES * 256];
__device__ __attribute__((aligned(256))) unsigned short g_bf1[(size_t)N_NODES * 256];
// split-bf16 transposed weights: [matrix][n*K + k]
__device__ __attribute__((aligned(256))) unsigned short g_Whi[6][256 * 256];
__device__ __attribute__((aligned(256))) unsigned short g_Wlo[6][256 * 256];

__device__ __forceinline__ unsigned short f2bf(float f) {
    unsigned int u = __float_as_uint(f);
    unsigned int r = (u + 0x7fffu + ((u >> 16) & 1u)) >> 16;   // RNE
    return (unsigned short)r;
}
__device__ __forceinline__ float bf2f(unsigned short h) {
    return __uint_as_float(((unsigned int)h) << 16);
}

// ---------------------------------------------------------------------------
// CSR build: zero -> degree count -> 3-kernel scan (scan3 also seeds cursor)
// -> atomic fill (4 edges/thread, no rowstart read).
// edge_index arrives as int32: [src[0..E-1], dst[0..E-1]]
// ---------------------------------------------------------------------------
__global__ void zero_kernel() {
    int i = blockIdx.x * blockDim.x + threadIdx.x;
    if (i < N_NODES) g_deg[i] = 0;
}

__global__ void deg_kernel(const int* __restrict__ ei) {
    int q = blockIdx.x * blockDim.x + threadIdx.x;   // quad index
    if (q >= N_EDGES / 4) return;
    int4 d4 = *(const int4*)(ei + N_EDGES + q * 4);
    if ((unsigned)d4.x < N_NODES) atomicAdd(&g_deg[d4.x], 1);
    if ((unsigned)d4.y < N_NODES) atomicAdd(&g_deg[d4.y], 1);
    if ((unsigned)d4.z < N_NODES) atomicAdd(&g_deg[d4.z], 1);
    if ((unsigned)d4.w < N_NODES) atomicAdd(&g_deg[d4.w], 1);
}

__global__ void scan1_kernel() {
    __shared__ int sm[256];
    int t = threadIdx.x;
    int idx = blockIdx.x * 256 + t;
    sm[t] = (idx < N_NODES) ? g_deg[idx] : 0;
    __syncthreads();
    for (int off = 128; off > 0; off >>= 1) {
        if (t < off) sm[t] += sm[t + off];
        __syncthreads();
    }
    if (t == 0) g_bsum[blockIdx.x] = sm[0];
}

__global__ void scan2_kernel(int nb) {
    __shared__ int sm[256];
    int t = threadIdx.x;
    int v = (t < nb) ? g_bsum[t] : 0;
    sm[t] = v;
    __syncthreads();
    for (int off = 1; off < 256; off <<= 1) {
        int tv = (t >= off) ? sm[t - off] : 0;
        __syncthreads();
        sm[t] += tv;
        __syncthreads();
    }
    g_boff[t] = sm[t] - v;                 // exclusive block offset
    if (t == nb - 1) g_rowstart[N_NODES] = sm[t];
}

__global__ void scan3_kernel() {
    __shared__ int sm[256];
    int t = threadIdx.x;
    int idx = blockIdx.x * 256 + t;
    int v = (idx < N_NODES) ? g_deg[idx] : 0;
    sm[t] = v;
    __syncthreads();
    for (int off = 1; off < 256; off <<= 1) {
        int tv = (t >= off) ? sm[t - off] : 0;
        __syncthreads();
        sm[t] += tv;
        __syncthreads();
    }
    if (idx < N_NODES) {
        int rs = g_boff[blockIdx.x] + sm[t] - v;
        g_rowstart[idx] = rs;
        g_cursor[idx] = rs;                // seed cursor = rowstart
    }
}

__global__ void fill_adj_kernel(const int* __restrict__ ei) {
    int q = blockIdx.x * blockDim.x + threadIdx.x;   // quad index
    if (q >= N_EDGES / 4) return;
    int4 s4 = *(const int4*)(ei + q * 4);
    int4 d4 = *(const int4*)(ei + N_EDGES + q * 4);
    // 4 independent atomic chains; cursor holds the absolute slot index
    if ((unsigned)d4.x < N_NODES) {
        int p = atomicAdd(&g_cursor[d4.x], 1);
        if ((unsigned)p < N_EDGES) g_adj[p] = ((unsigned)s4.x < N_NODES) ? s4.x : 0;
    }
    if ((unsigned)d4.y < N_NODES) {
        int p = atomicAdd(&g_cursor[d4.y], 1);
        if ((unsigned)p < N_EDGES) g_adj[p] = ((unsigned)s4.y < N_NODES) ? s4.y : 0;
    }
    if ((unsigned)d4.z < N_NODES) {
        int p = atomicAdd(&g_cursor[d4.z], 1);
        if ((unsigned)p < N_EDGES) g_adj[p] = ((unsigned)s4.z < N_NODES) ? s4.z : 0;
    }
    if ((unsigned)d4.w < N_NODES) {
        int p = atomicAdd(&g_cursor[d4.w], 1);
        if ((unsigned)p < N_EDGES) g_adj[p] = ((unsigned)s4.w < N_NODES) ? s4.w : 0;
    }
}

// ---------------------------------------------------------------------------
// Merged prep: segments for 6 weight matrices (split+transpose) + x->bf16.
// ---------------------------------------------------------------------------
__device__ __forceinline__ void prep_w_seg(const float* __restrict__ W, int K,
                                           int widx, int lbx, int tid) {
    int e = lbx * 256 + tid;
    if (e >= K * 256) return;
    int k = e >> 8, n = e & 255;
    float w = W[e];
    unsigned short hi = f2bf(w);
    unsigned short lo = f2bf(w - bf2f(hi));
    g_Whi[widx][n * K + k] = hi;
    g_Wlo[widx][n * K + k] = lo;
}

__global__ void prep_all_kernel(const float* __restrict__ x,
                                const float* __restrict__ Wl0, const float* __restrict__ Wr0,
                                const float* __restrict__ Wl1, const float* __restrict__ Wr1,
                                const float* __restrict__ Wl2, const float* __restrict__ Wr2) {
    int bx = blockIdx.x;
    int tid = threadIdx.x;
    if (bx < 128)        { prep_w_seg(Wl0, 128, 0, bx, tid);        return; }
    if (bx < 256)        { prep_w_seg(Wr0, 128, 1, bx - 128, tid);  return; }
    if (bx < 512)        { prep_w_seg(Wl1, 256, 2, bx - 256, tid);  return; }
    if (bx < 768)        { prep_w_seg(Wr1, 256, 3, bx - 512, tid);  return; }
    if (bx < 1024)       { prep_w_seg(Wl2, 256, 4, bx - 768, tid);  return; }
    if (bx < 1280)       { prep_w_seg(Wr2, 256, 5, bx - 1024, tid); return; }
    // conv x: 8 floats per thread
    long i = (long)(bx - 1280) * 256 + tid;       // oct index
    if (i >= (long)N_NODES * 128 / 8) return;
    const float* xp = x + i * 8;
    f32x4 v0 = *(const f32x4*)(xp);
    f32x4 v1 = *(const f32x4*)(xp + 4);
    s16x8 o;
    o[0] = (short)f2bf(v0.x); o[1] = (short)f2bf(v0.y);
    o[2] = (short)f2bf(v0.z); o[3] = (short)f2bf(v0.w);
    o[4] = (short)f2bf(v1.x); o[5] = (short)f2bf(v1.y);
    o[6] = (short)f2bf(v1.z); o[7] = (short)f2bf(v1.w);
    *(s16x8*)(g_bf0 + i * 8) = o;
}

// ---------------------------------------------------------------------------
// Mean aggregation, one WAVE per destination node. Lane layout:
// LPR = DIN/8 lanes per source row, each lane loads 16B (8 bf16);
// RPW = 64/LPR rows processed per issue; 4-deep manual unroll.
// ---------------------------------------------------------------------------
template <int DIN>
__global__ __launch_bounds__(256) void agg_wave_kernel(int sel) {
    const unsigned short* __restrict__ hb = sel == 0 ? g_bf0 : g_bf1;
    constexpr int LPR = DIN / 8;          // 16 (DIN=128) or 32 (DIN=256)
    constexpr int RPW = 64 / LPR;         // 4 or 2
    const int node = blockIdx.x * 4 + (threadIdx.x >> 6);
    if (node >= N_NODES) return;
    const int lane = threadIdx.x & 63;
    const int rg = lane / LPR;            // row-group
    const int cl = lane % LPR;            // column-lane (8 feats each)
    const int s = g_rowstart[node], e = g_rowstart[node + 1];

    float acc[8];
#pragma unroll
    for (int j = 0; j < 8; ++j) acc[j] = 0.f;

    int i = s;
    for (; i + 4 * RPW <= e; i += 4 * RPW) {
        int a0 = g_adj[i + 0 * RPW + rg];
        int a1 = g_adj[i + 1 * RPW + rg];
        int a2 = g_adj[i + 2 * RPW + rg];
        int a3 = g_adj[i + 3 * RPW + rg];
        s16x8 v0 = *(const s16x8*)(hb + (long)a0 * DIN + cl * 8);
        s16x8 v1 = *(const s16x8*)(hb + (long)a1 * DIN + cl * 8);
        s16x8 v2 = *(const s16x8*)(hb + (long)a2 * DIN + cl * 8);
        s16x8 v3 = *(const s16x8*)(hb + (long)a3 * DIN + cl * 8);
#pragma unroll
        for (int j = 0; j < 8; ++j)
            acc[j] += bf2f((unsigned short)v0[j]) + bf2f((unsigned short)v1[j])
                    + bf2f((unsigned short)v2[j]) + bf2f((unsigned short)v3[j]);
    }
    for (; i < e; i += RPW) {
        int eidx = i + rg;
        if (eidx < e) {
            int a = g_adj[eidx];
            s16x8 v = *(const s16x8*)(hb + (long)a * DIN + cl * 8);
#pragma unroll
            for (int j = 0; j < 8; ++j) acc[j] += bf2f((unsigned short)v[j]);
        }
    }

#pragma unroll
    for (int j = 0; j < 8; ++j) {
        if (RPW == 4) acc[j] += __shfl_xor(acc[j], 16, 64);
        acc[j] += __shfl_xor(acc[j], 32, 64);
    }

    if (rg == 0) {
        float inv = 1.f / fmaxf((float)(e - s), 1.f);
        s16x8 ov;
#pragma unroll
        for (int j = 0; j < 8; ++j) ov[j] = (short)f2bf(acc[j] * inv);
        *(s16x8*)(g_aggbf + (long)node * DIN + cl * 8) = ov;
    }
}

// ---------------------------------------------------------------------------
// MFMA dual GEMM, pure-bf16 A, split-bf16 W (2 MFMA/frag):
//   out = aggbf @ W[widx] + bf[a2_sel] @ W[widx+1] + bias (+ReLU)
// Block 256 thr (4 waves). BM=256, BN=64, BK=64, mfma_f32_32x32x16_bf16.
// XCD-aware bijective mapping; T14 register prefetch of next K-step.
// LDS rows 128B, XOR-swizzle byte ^= (row&7)<<4. 48KB -> 3 blocks/CU.
// ---------------------------------------------------------------------------
template <int K, bool RELU, bool FP32OUT>
__global__ __launch_bounds__(256, 3) void gemm2_mfma(
    int a2_sel, int widx, const float* __restrict__ bias,
    float* __restrict__ outp, int bfsel) {
    __shared__ __attribute__((aligned(16))) char lds[49152];
    char* const As = lds;            // 256 rows * 128B
    char* const Wh = lds + 32768;    // 64 rows * 128B
    char* const Wl = lds + 40960;    // 64 rows * 128B

    const int tid = threadIdx.x;
    const int w = tid >> 6;
    const int l = tid & 63;
    const int l31 = l & 31;
    const int lh = l >> 5;                 // 0/1
    // XCD-aware mapping (8 XCDs, round-robin bx%8)
    const int bx = blockIdx.x;
    const int xcd = bx & 7;
    const int idx = bx >> 3;               // 0..99
    const int mblk = (idx >> 2) * 8 + xcd; // 0..199
    const int nblk = idx & 3;
    if (mblk >= MBLKS) return;
    const long row0 = (long)mblk * 256;
    const int ncol0 = nblk * 64;

    f32x16 acc[2][2];
#pragma unroll
    for (int i = 0; i < 2; ++i)
#pragma unroll
        for (int j = 0; j < 2; ++j) acc[i][j] = (f32x16)0.f;

    const int sar = tid >> 3;              // A stage: base row 0..31 (+j*32)
    const int sac = tid & 7;               // A stage: 16B chunk 0..7
    const int swn = tid >> 2;              // W stage: n-row 0..63
    const int swc = (tid & 3) * 2;         // W stage: chunk base

    const unsigned short* A2p = a2_sel == 0 ? (const unsigned short*)g_bf0
                                            : (const unsigned short*)g_bf1;
    constexpr int NPP = K / 64;            // K-steps per pass
    constexpr int NT = NPP * 2;            // total steps (2 passes)

    s16x8 aR[8], whR[2], wlR[2];
    auto issue = [&](int t) {
        int pass = (t >= NPP) ? 1 : 0;
        int kc = (t - pass * NPP) * 64;
        const unsigned short* A = pass ? A2p : (const unsigned short*)g_aggbf;
        const unsigned short* WH = g_Whi[widx + pass] + (long)ncol0 * K;
        const unsigned short* WL = g_Wlo[widx + pass] + (long)ncol0 * K;
#pragma unroll
        for (int j = 0; j < 8; ++j) {
            int r = j * 32 + sar;
            long grow = row0 + r; if (grow > N_NODES - 1) grow = N_NODES - 1;
            aR[j] = *(const s16x8*)(A + grow * K + kc + sac * 8);
        }
#pragma unroll
        for (int q = 0; q < 2; ++q) {
            int c = swc + q;
            whR[q] = *(const s16x8*)(WH + (long)swn * K + kc + c * 8);
            wlR[q] = *(const s16x8*)(WL + (long)swn * K + kc + c * 8);
        }
    };

    issue(0);
    for (int t = 0; t < NT; ++t) {
        // write staged regs -> LDS (waits the global loads)
#pragma unroll
        for (int j = 0; j < 8; ++j) {
            int r = j * 32 + sar;
            *(s16x8*)(As + r * 128 + ((sac * 16) ^ ((r & 7) << 4))) = aR[j];
        }
#pragma unroll
        for (int q = 0; q < 2; ++q) {
            int c = swc + q;
            int o = swn * 128 + ((c * 16) ^ ((swn & 7) << 4));
            *(s16x8*)(Wh + o) = whR[q];
            *(s16x8*)(Wl + o) = wlR[q];
        }
        __syncthreads();
        if (t + 1 < NT) issue(t + 1);     // prefetch next step (T14)
#pragma unroll
        for (int ks = 0; ks < 4; ++ks) {
            const int kb = ks * 32 + lh * 16;
            s16x8 af[2], bh[2], bl[2];
#pragma unroll
            for (int mi = 0; mi < 2; ++mi) {
                int r = w * 64 + mi * 32 + l31;
                af[mi] = *(const s16x8*)(As + r * 128 + (kb ^ ((r & 7) << 4)));
            }
#pragma unroll
            for (int ni = 0; ni < 2; ++ni) {
                int n = ni * 32 + l31;
                int o = n * 128 + (kb ^ ((n & 7) << 4));
                bh[ni] = *(const s16x8*)(Wh + o);
                bl[ni] = *(const s16x8*)(Wl + o);
            }
#pragma unroll
            for (int mi = 0; mi < 2; ++mi)
#pragma unroll
                for (int ni = 0; ni < 2; ++ni)
                    acc[mi][ni] = __builtin_amdgcn_mfma_f32_32x32x16_bf16(af[mi], bh[ni], acc[mi][ni], 0, 0, 0);
#pragma unroll
            for (int mi = 0; mi < 2; ++mi)
#pragma unroll
                for (int ni = 0; ni < 2; ++ni)
                    acc[mi][ni] = __builtin_amdgcn_mfma_f32_32x32x16_bf16(af[mi], bl[ni], acc[mi][ni], 0, 0, 0);
        }
        __syncthreads();
    }

    // epilogue: C/D layout col = lane&31, row = (reg&3)+8*(reg>>2)+4*(lane>>5)
    unsigned short* bfout = bfsel == 0 ? g_bf0 : g_bf1;
#pragma unroll
    for (int ni = 0; ni < 2; ++ni) {
        int col = ncol0 + ni * 32 + l31;
        float bv = bias[col];
#pragma unroll
        for (int mi = 0; mi < 2; ++mi) {
#pragma unroll
            for (int reg = 0; reg < 16; ++reg) {
                int lr = (reg & 3) + 8 * (reg >> 2) + 4 * lh;
                long grow = row0 + w * 64 + mi * 32 + lr;
                if (grow < N_NODES) {
                    float v = acc[mi][ni][reg] + bv;
                    if (RELU) v = fmaxf(v, 0.f);
                    if (FP32OUT) outp[grow * 256 + col] = v;
                    else bfout[grow * 256 + col] = f2bf(v);
                }
            }
        }
    }
}

// ---------------------------------------------------------------------------
extern "C" void kernel_launch(void* const* d_in, const int* in_sizes, int n_in,
                              void* d_out, int out_size, void* d_ws, size_t ws_size,
                              hipStream_t stream) {
    const float* x = (const float*)d_in[0];
    const int* ei = (const int*)d_in[1];        // int32 [2, E]
    const float* Wl0 = (const float*)d_in[2];
    const float* b0  = (const float*)d_in[3];
    const float* Wr0 = (const float*)d_in[4];
    const float* Wl1 = (const float*)d_in[5];
    const float* b1  = (const float*)d_in[6];
    const float* Wr1 = (const float*)d_in[7];
    const float* Wl2 = (const float*)d_in[8];
    const float* b2  = (const float*)d_in[9];
    const float* Wr2 = (const float*)d_in[10];
    float* out = (float*)d_out;

    int nblocks = (N_NODES + 255) / 256;   // 196
    int qblocks = (N_EDGES / 4 + 255) / 256;   // 782

    zero_kernel<<<nblocks, 256, 0, stream>>>();
    deg_kernel<<<qblocks, 256, 0, stream>>>(ei);
    scan1_kernel<<<nblocks, 256, 0, stream>>>();
    scan2_kernel<<<1, 256, 0, stream>>>(nblocks);
    scan3_kernel<<<nblocks, 256, 0, stream>>>();
    fill_adj_kernel<<<qblocks, 256, 0, stream>>>(ei);

    // merged weight prep + x->bf16: 1280 W-blocks + 3125 conv-blocks
    prep_all_kernel<<<1280 + 3125, 256, 0, stream>>>(x, Wl0, Wr0, Wl1, Wr1, Wl2, Wr2);

    int gblocks = 800;                    // 8 xcd x 25 mloc x 4 nblk
    int ablocks = (N_NODES + 3) / 4;      // 12500 (4 waves/block, 1 node/wave)

    // Layer 0: din=128   (agg <- g_bf0, root <- g_bf0, out -> g_bf1 bf16)
    agg_wave_kernel<128><<<ablocks, 256, 0, stream>>>(0);
    gemm2_mfma<128, true, false><<<gblocks, 256, 0, stream>>>(0, 0, b0, nullptr, 1);

    // Layer 1: din=256   (agg <- g_bf1, root <- g_bf1, out -> g_bf0 bf16)
    agg_wave_kernel<256><<<ablocks, 256, 0, stream>>>(1);
    gemm2_mfma<256, true, false><<<gblocks, 256, 0, stream>>>(1, 2, b1, nullptr, 0);

    // Layer 2: din=256, no ReLU  (agg <- g_bf0, root <- g_bf0, out -> d_out fp32)
    agg_wave_kernel<256><<<ablocks, 256, 0, stream>>>(0);
    gemm2_mfma<256, false, true><<<gblocks, 256, 0, stream>>>(0, 4, b2, out, 1);
}